// Round 1
// baseline (1166.914 us; speedup 1.0000x reference)
//
#include <hip/hip_runtime.h>
#include <math.h>

#define BB    32
#define CCH   64
#define DIMN  1024
#define NCLS  10

typedef __attribute__((ext_vector_type(8))) short bf16x8;
typedef __attribute__((ext_vector_type(4))) float f32x4;
typedef __attribute__((ext_vector_type(4))) unsigned short us4;
typedef __attribute__((ext_vector_type(8))) unsigned short us8;

#define MFMA16(a, b, c) __builtin_amdgcn_mfma_f32_16x16x32_bf16(a, b, c, 0, 0, 0)

__device__ __forceinline__ unsigned short f2bf(float x) {
  unsigned u = __float_as_uint(x);
  unsigned r = u + 0x7fffu + ((u >> 16) & 1u);   // round-to-nearest-even
  return (unsigned short)(r >> 16);
}
__device__ __forceinline__ float bf2f(unsigned short h) {
  return __uint_as_float(((unsigned)h) << 16);
}
// x == h + m + l to ~2^-26 relative
__device__ __forceinline__ void split3(float x, unsigned short& h,
                                       unsigned short& m, unsigned short& l) {
  h = f2bf(x); float hf = bf2f(h);
  float r = x - hf;
  m = f2bf(r); float mf = bf2f(m);
  l = f2bf(r - mf);
}
__device__ __forceinline__ bf16x8 ld16B(const unsigned short* p) {
  union { us8 u; bf16x8 v; } c;
  c.u = *(const us8*)p;           // 16B-aligned -> ds_read_b128
  return c.v;
}

// ---------------------------------------------------------------------------
// 1) transpose: image (B,C,DIM) -> X (B,DIM,C)
// ---------------------------------------------------------------------------
__global__ __launch_bounds__(256) void k_transpose(const float* __restrict__ img,
                                                   float* __restrict__ X) {
  __shared__ float tile[64][65];
  const int b  = blockIdx.y;
  const int n0 = blockIdx.x * 64;
  const int tx = threadIdx.x & 63;
  const int ty = threadIdx.x >> 6;
  const float* src = img + (size_t)b * CCH * DIMN;
  #pragma unroll
  for (int c = ty; c < 64; c += 4)
    tile[c][tx] = src[(size_t)c * DIMN + n0 + tx];
  __syncthreads();
  float* dst = X + (size_t)b * DIMN * CCH;
  #pragma unroll
  for (int nn = ty; nn < 64; nn += 4)
    dst[(size_t)(n0 + nn) * CCH + tx] = tile[tx][nn];
}

// ---------------------------------------------------------------------------
// 1b) weight transpose: Wt[m][c][j] = Wm[j][c], m in {Q,K,V}. 3 x 4096 floats.
//     Pure data movement (no numeric change); lets qkv kernels read float4
//     along j instead of 192 scalar stride-256B loads per thread.
// ---------------------------------------------------------------------------
__global__ __launch_bounds__(256) void k_wtrans(
    const float* __restrict__ W0, const float* __restrict__ W1,
    const float* __restrict__ W2, float* __restrict__ T) {
  __shared__ float t[64][65];
  const float* W = (blockIdx.x == 0) ? W0 : ((blockIdx.x == 1) ? W1 : W2);
  const int x  = threadIdx.x & 63;
  const int y4 = threadIdx.x >> 6;
  #pragma unroll
  for (int y = y4; y < 64; y += 4) t[y][x] = W[y * 64 + x];
  __syncthreads();
  float* dst = T + (size_t)blockIdx.x * 4096;
  #pragma unroll
  for (int y = y4; y < 64; y += 4) dst[y * 64 + x] = t[x][y];
}

// ---------------------------------------------------------------------------
// shared qkv inner loop: bitwise-identical accumulation order (j ascending
// per accumulator chain), vectorized loads. Wt = [3][64][64] transposed.
// ---------------------------------------------------------------------------
__device__ __forceinline__ void qkv_body(
    const float xs[16][64], const float* __restrict__ Wt, int c, int tg,
    float qa[4], float ka[4], float va[4]) {
  const float* WQt = Wt + (size_t)c * 64;
  const float* WKt = Wt + 4096 + (size_t)c * 64;
  const float* WVt = Wt + 8192 + (size_t)c * 64;
  for (int j = 0; j < 64; j += 4) {
    const float4 wq = *(const float4*)(WQt + j);
    const float4 wk = *(const float4*)(WKt + j);
    const float4 wv = *(const float4*)(WVt + j);
    #pragma unroll
    for (int r = 0; r < 4; ++r) {
      const float4 xv = *(const float4*)&xs[tg * 4 + r][j];
      qa[r] = fmaf(xv.x, wq.x, qa[r]);
      qa[r] = fmaf(xv.y, wq.y, qa[r]);
      qa[r] = fmaf(xv.z, wq.z, qa[r]);
      qa[r] = fmaf(xv.w, wq.w, qa[r]);
      ka[r] = fmaf(xv.x, wk.x, ka[r]);
      ka[r] = fmaf(xv.y, wk.y, ka[r]);
      ka[r] = fmaf(xv.z, wk.z, ka[r]);
      ka[r] = fmaf(xv.w, wk.w, ka[r]);
      va[r] = fmaf(xv.x, wv.x, va[r]);
      va[r] = fmaf(xv.y, wv.y, va[r]);
      va[r] = fmaf(xv.z, wv.z, va[r]);
      va[r] = fmaf(xv.w, wv.w, va[r]);
    }
  }
}

// ---------------------------------------------------------------------------
// 2) QKV + per-layer pre-split: Q fp32; K 3-term bf16 [t][c];
//    V 3-term bf16 transposed+tiled [b][kt][c][32]
// ---------------------------------------------------------------------------
__global__ __launch_bounds__(256) void k_qkv_split(
    const float* __restrict__ X, const float* __restrict__ Wt,
    float* __restrict__ Q,
    unsigned short* __restrict__ Kh, unsigned short* __restrict__ Km,
    unsigned short* __restrict__ Kl,
    unsigned short* __restrict__ VhT, unsigned short* __restrict__ VmT,
    unsigned short* __restrict__ VlT) {
  __shared__ float xs[16][64];
  __shared__ unsigned short vs[3][16][64];
  const int c  = threadIdx.x & 63;
  const int tg = threadIdx.x >> 6;
  const size_t t0 = (size_t)blockIdx.x * 16;
  #pragma unroll
  for (int r = tg; r < 16; r += 4)
    xs[r][c] = X[(t0 + r) * 64 + c];
  __syncthreads();
  float qa[4] = {0.f,0.f,0.f,0.f};
  float ka[4] = {0.f,0.f,0.f,0.f};
  float va[4] = {0.f,0.f,0.f,0.f};
  qkv_body(xs, Wt, c, tg, qa, ka, va);
  #pragma unroll
  for (int r = 0; r < 4; ++r) {
    const int t = tg * 4 + r;
    const size_t idx = (t0 + t) * 64 + c;
    Q[idx] = qa[r];
    unsigned short h, m, l;
    split3(ka[r], h, m, l);
    Kh[idx] = h; Km[idx] = m; Kl[idx] = l;
    split3(va[r], h, m, l);
    vs[0][t][c] = h; vs[1][t][c] = m; vs[2][t][c] = l;
  }
  __syncthreads();
  {
    const int row  = threadIdx.x >> 2;
    const int part = threadIdx.x & 3;
    const size_t bofs = (t0 >> 10) * ((size_t)DIMN * 64);
    const size_t kt   = (t0 & 1023) >> 5;
    const size_t tin  = (t0 & 31) + part * 4;
    unsigned short* dst[3] = {VhT, VmT, VlT};
    #pragma unroll
    for (int term = 0; term < 3; ++term) {
      us4 pk;
      #pragma unroll
      for (int i = 0; i < 4; ++i) pk[i] = vs[term][part * 4 + i][row];
      *(us4*)&dst[term][bofs + kt * 2048 + (size_t)row * 32 + tin] = pk;
    }
  }
}

// ---------------------------------------------------------------------------
// 2b) QKV with FUSED SPLIT-K MERGE of the previous layer.
// ---------------------------------------------------------------------------
__global__ __launch_bounds__(256) void k_qkv_merge(
    float* __restrict__ X,
    const float* __restrict__ Mp, const float* __restrict__ Lp,
    const float* __restrict__ Op,
    const float* __restrict__ Wt,
    float* __restrict__ Q,
    unsigned short* __restrict__ Kh, unsigned short* __restrict__ Km,
    unsigned short* __restrict__ Kl,
    unsigned short* __restrict__ VhT, unsigned short* __restrict__ VmT,
    unsigned short* __restrict__ VlT) {
  __shared__ float xs[16][64];
  __shared__ unsigned short vs[3][16][64];
  const int c  = threadIdx.x & 63;
  const int tg = threadIdx.x >> 6;
  const size_t t0 = (size_t)blockIdx.x * 16;
  #pragma unroll
  for (int r = tg; r < 16; r += 4) {
    const size_t grow = t0 + r;                 // global row 0..32767
    const float m0 = Mp[grow], m1 = Mp[32768 + grow];
    const float l0 = Lp[grow], l1 = Lp[32768 + grow];
    const float mm = fmaxf(m0, m1);
    const float w0 = __expf(m0 - mm), w1 = __expf(m1 - mm);
    const float inv = 1.0f / (l0 * w0 + l1 * w1);
    const float o0 = Op[grow * 64 + c];
    const float o1 = Op[(size_t)2097152 + grow * 64 + c];
    const float xn = X[grow * 64 + c] + (o0 * w0 + o1 * w1) * inv;
    X[grow * 64 + c] = xn;
    xs[r][c] = xn;
  }
  __syncthreads();
  float qa[4] = {0.f,0.f,0.f,0.f};
  float ka[4] = {0.f,0.f,0.f,0.f};
  float va[4] = {0.f,0.f,0.f,0.f};
  qkv_body(xs, Wt, c, tg, qa, ka, va);
  #pragma unroll
  for (int r = 0; r < 4; ++r) {
    const int t = tg * 4 + r;
    const size_t idx = (t0 + t) * 64 + c;
    Q[idx] = qa[r];
    unsigned short h, m, l;
    split3(ka[r], h, m, l);
    Kh[idx] = h; Km[idx] = m; Kl[idx] = l;
    split3(va[r], h, m, l);
    vs[0][t][c] = h; vs[1][t][c] = m; vs[2][t][c] = l;
  }
  __syncthreads();
  {
    const int row  = threadIdx.x >> 2;
    const int part = threadIdx.x & 3;
    const size_t bofs = (t0 >> 10) * ((size_t)DIMN * 64);
    const size_t kt   = (t0 & 1023) >> 5;
    const size_t tin  = (t0 & 31) + part * 4;
    unsigned short* dst[3] = {VhT, VmT, VlT};
    #pragma unroll
    for (int term = 0; term < 3; ++term) {
      us4 pk;
      #pragma unroll
      for (int i = 0; i < 4; ++i) pk[i] = vs[term][part * 4 + i][row];
      *(us4*)&dst[term][bofs + kt * 2048 + (size_t)row * 32 + tin] = pk;
    }
  }
}

// ---------------------------------------------------------------------------
// 3) MFMA flash attention, SPLIT-K (2 halves), with register prefetch of the
//    next K/V tile (T14: global-load latency hides under the compute phase)
//    and s_setprio around the MFMA clusters (T5: 4 independent blocks/CU ->
//    wave role diversity). Arithmetic bitwise-identical to prior version.
// ---------------------------------------------------------------------------
__global__ __launch_bounds__(256, 4) void k_attn_sk(
    const float* __restrict__ Qg,
    const unsigned short* __restrict__ Kh, const unsigned short* __restrict__ Km,
    const unsigned short* __restrict__ Kl,
    const unsigned short* __restrict__ VhT, const unsigned short* __restrict__ VmT,
    const unsigned short* __restrict__ VlT,
    float* __restrict__ Mp, float* __restrict__ Lp, float* __restrict__ Op) {
  __shared__ __align__(16) unsigned short Khs[32 * 72];
  __shared__ __align__(16) unsigned short Kms[32 * 72];
  __shared__ __align__(16) unsigned short Kls[32 * 72];
  __shared__ __align__(16) unsigned short Vhs[64 * 40];   // V^T: [c][j]
  __shared__ __align__(16) unsigned short Vms[64 * 40];
  __shared__ __align__(16) unsigned short Vls[64 * 40];
  __shared__ __align__(16) float Pb[64 * 36];             // fp32 P round-trip

  const int tid  = threadIdx.x;
  const int w    = tid >> 6;
  const int lane = tid & 63;
  const int ln   = lane & 15;
  const int q    = lane >> 4;

  // XCD-aware swizzle: 1024 blocks; batch pinned to one XCD (locality only)
  const int bid   = blockIdx.x;            // 0..1023
  const int xcd   = bid & 7;
  const int seq   = bid >> 3;              // 0..127
  const int b     = xcd * 4 + (seq >> 5);  // 4 batches per XCD
  const int local = seq & 31;
  const int half  = local >> 4;            // K-split half
  const int i0    = (local & 15) * 64;     // Q tile

  const size_t base = (size_t)b * (DIMN * 64);
  const float scale = 0.03125f;

  const int kj = tid >> 3, kg = tid & 7;
  const int vc = tid >> 2, vg = tid & 3;
  const int klo = kj * 72 + kg * 8;
  const int vlo = vc * 40 + vg * 8;

  // ---- Q fragments: 3-term split, 2 k-chunks (once per block) --------------
  bf16x8 qh[2], qm[2], ql[2];
  {
    const int mrow = i0 + 16 * w + ln;
    const float* qp = Qg + base + (size_t)mrow * 64 + 8 * q;
    #pragma unroll
    for (int s = 0; s < 2; ++s) {
      const float4 x0 = ((const float4*)(qp + 32 * s))[0];
      const float4 x1 = ((const float4*)(qp + 32 * s))[1];
      const float xv[8] = {x0.x, x0.y, x0.z, x0.w, x1.x, x1.y, x1.z, x1.w};
      union { bf16x8 v; unsigned short e[8]; } uh, um, ul;
      #pragma unroll
      for (int j = 0; j < 8; ++j) {
        unsigned short h, m, l;
        split3(xv[j], h, m, l);
        uh.e[j] = h; um.e[j] = m; ul.e[j] = l;
      }
      qh[s] = uh.v; qm[s] = um.v; ql[s] = ul.v;
    }
  }

  f32x4 O[4];
  #pragma unroll
  for (int ct = 0; ct < 4; ++ct) O[ct] = (f32x4){0.f, 0.f, 0.f, 0.f};
  float m_run[4] = {-INFINITY, -INFINITY, -INFINITY, -INFINITY};
  float l_run[4] = {0.f, 0.f, 0.f, 0.f};

  const int kt0 = half * 16;

  // prologue prefetch of the first tile into registers
  us8 ra0, ra1, ra2, rb0, rb1, rb2;
  {
    const size_t tof = base + (size_t)kt0 * 2048 + tid * 8;
    ra0 = *(const us8*)&Kh[tof];
    ra1 = *(const us8*)&Km[tof];
    ra2 = *(const us8*)&Kl[tof];
    rb0 = *(const us8*)&VhT[tof];
    rb1 = *(const us8*)&VmT[tof];
    rb2 = *(const us8*)&VlT[tof];
  }

  for (int kt = kt0; kt < kt0 + 16; ++kt) {
    __syncthreads();   // previous iteration's K/V readers done

    // ---- write prefetched tile regs -> LDS ---------------------------------
    *(us8*)&Khs[klo] = ra0;
    *(us8*)&Kms[klo] = ra1;
    *(us8*)&Kls[klo] = ra2;
    *(us8*)&Vhs[vlo] = rb0;
    *(us8*)&Vms[vlo] = rb1;
    *(us8*)&Vls[vlo] = rb2;
    __syncthreads();

    // ---- issue next tile's global loads; latency hides under compute -------
    if (kt + 1 < kt0 + 16) {
      const size_t tof = base + (size_t)(kt + 1) * 2048 + tid * 8;
      ra0 = *(const us8*)&Kh[tof];
      ra1 = *(const us8*)&Km[tof];
      ra2 = *(const us8*)&Kl[tof];
      rb0 = *(const us8*)&VhT[tof];
      rb1 = *(const us8*)&VmT[tof];
      rb2 = *(const us8*)&VlT[tof];
    }

    // ---- S strip = Q . K^T via 6-product compensated MFMA (r5 order) -------
    f32x4 sacc[2];
    __builtin_amdgcn_s_setprio(1);
    #pragma unroll
    for (int ct = 0; ct < 2; ++ct) {
      f32x4 a = (f32x4){0.f, 0.f, 0.f, 0.f};
      #pragma unroll
      for (int s = 0; s < 2; ++s) {
        const int ko = (16 * ct + ln) * 72 + 32 * s + 8 * q;
        const bf16x8 bh = ld16B(&Khs[ko]);
        const bf16x8 bm = ld16B(&Kms[ko]);
        const bf16x8 bl = ld16B(&Kls[ko]);
        a = MFMA16(ql[s], bh, a);
        a = MFMA16(qh[s], bl, a);
        a = MFMA16(qm[s], bm, a);
        a = MFMA16(qm[s], bh, a);
        a = MFMA16(qh[s], bm, a);
        a = MFMA16(qh[s], bh, a);
      }
      sacc[ct] = a;
    }
    __builtin_amdgcn_s_setprio(0);

    // ---- wave-local online softmax (identical arithmetic) ------------------
    float rmax[4];
    #pragma unroll
    for (int r = 0; r < 4; ++r)
      rmax[r] = fmaxf(sacc[0][r], sacc[1][r]);
    #pragma unroll
    for (int mk = 1; mk <= 8; mk <<= 1) {
      #pragma unroll
      for (int r = 0; r < 4; ++r)
        rmax[r] = fmaxf(rmax[r], __shfl_xor(rmax[r], mk, 64));
    }
    float alpha[4], rsum[4];
    #pragma unroll
    for (int r = 0; r < 4; ++r) {
      const float mnew = fmaxf(m_run[r], rmax[r] * scale);
      alpha[r] = __expf(m_run[r] - mnew);
      m_run[r] = mnew;
      rsum[r] = 0.f;
    }
    #pragma unroll
    for (int ct = 0; ct < 2; ++ct) {
      #pragma unroll
      for (int r = 0; r < 4; ++r) {
        const float pv = __expf(sacc[ct][r] * scale - m_run[r]);
        rsum[r] += pv;
        Pb[(16 * w + 4 * q + r) * 36 + ln + 16 * ct] = pv;   // fp32, wave-local
      }
    }
    #pragma unroll
    for (int mk = 1; mk <= 8; mk <<= 1) {
      #pragma unroll
      for (int r = 0; r < 4; ++r)
        rsum[r] += __shfl_xor(rsum[r], mk, 64);
    }
    #pragma unroll
    for (int r = 0; r < 4; ++r)
      l_run[r] = l_run[r] * alpha[r] + rsum[r];

    #pragma unroll
    for (int ct = 0; ct < 4; ++ct) {
      #pragma unroll
      for (int r = 0; r < 4; ++r) O[ct][r] *= alpha[r];
    }

    // ---- P A-fragment: own rows, fp32 -> 3-term split ----------------------
    bf16x8 ph, pm, pl;
    {
      const float* pp = &Pb[(16 * w + ln) * 36 + 8 * q];
      const float4 p0 = ((const float4*)pp)[0];
      const float4 p1 = ((const float4*)pp)[1];
      const float pvv[8] = {p0.x, p0.y, p0.z, p0.w, p1.x, p1.y, p1.z, p1.w};
      union { bf16x8 v; unsigned short e[8]; } uh, um, ul;
      #pragma unroll
      for (int j = 0; j < 8; ++j) {
        unsigned short h, m, l;
        split3(pvv[j], h, m, l);
        uh.e[j] = h; um.e[j] = m; ul.e[j] = l;
      }
      ph = uh.v; pm = um.v; pl = ul.v;
    }

    // ---- O += P @ V, 6-product (r5 order) ----------------------------------
    __builtin_amdgcn_s_setprio(1);
    #pragma unroll
    for (int ct = 0; ct < 4; ++ct) {
      const int vo = (16 * ct + ln) * 40 + 8 * q;
      const bf16x8 vvh = ld16B(&Vhs[vo]);
      const bf16x8 vvm = ld16B(&Vms[vo]);
      const bf16x8 vvl = ld16B(&Vls[vo]);
      O[ct] = MFMA16(ph, vvh, O[ct]);
      O[ct] = MFMA16(ph, vvm, O[ct]);
      O[ct] = MFMA16(pm, vvh, O[ct]);
      O[ct] = MFMA16(pm, vvm, O[ct]);
      O[ct] = MFMA16(ph, vvl, O[ct]);
      O[ct] = MFMA16(pl, vvh, O[ct]);
    }
    __builtin_amdgcn_s_setprio(0);
  }

  // ---- epilogue: write split-K partials (m, l, raw O) ----------------------
  const size_t hofs = (size_t)half * (32 * 1024);
  #pragma unroll
  for (int r = 0; r < 4; ++r) {
    const int row = i0 + 16 * w + 4 * q + r;
    const size_t grow = hofs + (size_t)b * DIMN + row;
    #pragma unroll
    for (int ct = 0; ct < 4; ++ct)
      Op[grow * 64 + ln + 16 * ct] = O[ct][r];
    if (ln == 0) { Mp[grow] = m_run[r]; Lp[grow] = l_run[r]; }
  }
}

// ---------------------------------------------------------------------------
// 3b) final merge + channel-mean (layer 7 partials): 256 blocks x 128 tokens
// ---------------------------------------------------------------------------
__global__ __launch_bounds__(256) void k_merge_mean(
    const float* __restrict__ X,
    const float* __restrict__ Mp, const float* __restrict__ Lp,
    const float* __restrict__ Op, float* __restrict__ meanv) {
  const int c  = threadIdx.x & 63;
  const int tg = threadIdx.x >> 6;
  const size_t t0 = (size_t)blockIdx.x * 128;
  for (int i = tg; i < 128; i += 4) {
    const size_t grow = t0 + i;
    const float m0 = Mp[grow], m1 = Mp[32768 + grow];
    const float l0 = Lp[grow], l1 = Lp[32768 + grow];
    const float mm = fmaxf(m0, m1);
    const float w0 = __expf(m0 - mm), w1 = __expf(m1 - mm);
    const float inv = 1.0f / (l0 * w0 + l1 * w1);
    const float o0 = Op[grow * 64 + c];
    const float o1 = Op[(size_t)2097152 + grow * 64 + c];
    float v = X[grow * 64 + c] + (o0 * w0 + o1 * w1) * inv;
    #pragma unroll
    for (int off = 32; off > 0; off >>= 1)
      v += __shfl_down(v, off, 64);
    if (c == 0) meanv[grow] = v * (1.0f / 64.0f);
  }
}

// ---------------------------------------------------------------------------
// 4) head stage 2: pred[b,k] = meanv[b,:] . last_W[k,:] + last_b[k]
// ---------------------------------------------------------------------------
__global__ __launch_bounds__(256) void k_head2(
    const float* __restrict__ meanv, const float* __restrict__ lW,
    const float* __restrict__ lb, float* __restrict__ out) {
  __shared__ float red[256];
  const int b   = blockIdx.x;
  const int tid = threadIdx.x;
  float acc[NCLS];
  #pragma unroll
  for (int k = 0; k < NCLS; ++k) acc[k] = 0.f;
  for (int n = tid; n < DIMN; n += 256) {
    const float m = meanv[(size_t)b * DIMN + n];
    #pragma unroll
    for (int k = 0; k < NCLS; ++k)
      acc[k] = fmaf(m, lW[k * DIMN + n], acc[k]);
  }
  for (int k = 0; k < NCLS; ++k) {
    red[tid] = acc[k];
    __syncthreads();
    for (int s = 128; s > 0; s >>= 1) {
      if (tid < s) red[tid] += red[tid + s];
      __syncthreads();
    }
    if (tid == 0) out[b * NCLS + k] = red[0] + lb[k];
    __syncthreads();
  }
}

// ===========================================================================
// MIDDLE-TIER PATH (r8 kernel, ws >= 41 MB but < split-K need): proven 0.0
// ===========================================================================
__global__ __launch_bounds__(256) void k_attn_s(
    const float* __restrict__ Qg,
    const unsigned short* __restrict__ Kh, const unsigned short* __restrict__ Km,
    const unsigned short* __restrict__ Kl,
    const unsigned short* __restrict__ VhT, const unsigned short* __restrict__ VmT,
    const unsigned short* __restrict__ VlT,
    float* __restrict__ X, float* __restrict__ meanout) {
  __shared__ __align__(16) unsigned short Khs[32 * 72];
  __shared__ __align__(16) unsigned short Kms[32 * 72];
  __shared__ __align__(16) unsigned short Kls[32 * 72];
  __shared__ __align__(16) unsigned short Vhs[64 * 40];
  __shared__ __align__(16) unsigned short Vms[64 * 40];
  __shared__ __align__(16) unsigned short Vls[64 * 40];
  __shared__ __align__(16) float Pb[64 * 36];

  const int tid  = threadIdx.x;
  const int w    = tid >> 6;
  const int lane = tid & 63;
  const int ln   = lane & 15;
  const int q    = lane >> 4;
  const int bid = blockIdx.x;
  const int xcd = bid & 7;
  const int seq = bid >> 3;
  const int b   = xcd * 4 + (seq >> 4);
  const int i0  = (seq & 15) * 64;
  const size_t base = (size_t)b * (DIMN * 64);
  const float scale = 0.03125f;

  const int kj = tid >> 3, kg = tid & 7;
  const int vc = tid >> 2, vg = tid & 3;
  const int klo = kj * 72 + kg * 8;
  const int vlo = vc * 40 + vg * 8;

  bf16x8 qh[2], qm[2], ql[2];
  {
    const int mrow = i0 + 16 * w + ln;
    const float* qp = Qg + base + (size_t)mrow * 64 + 8 * q;
    #pragma unroll
    for (int s = 0; s < 2; ++s) {
      const float4 x0 = ((const float4*)(qp + 32 * s))[0];
      const float4 x1 = ((const float4*)(qp + 32 * s))[1];
      const float xv[8] = {x0.x, x0.y, x0.z, x0.w, x1.x, x1.y, x1.z, x1.w};
      union { bf16x8 v; unsigned short e[8]; } uh, um, ul;
      #pragma unroll
      for (int j = 0; j < 8; ++j) {
        unsigned short h, m, l;
        split3(xv[j], h, m, l);
        uh.e[j] = h; um.e[j] = m; ul.e[j] = l;
      }
      qh[s] = uh.v; qm[s] = um.v; ql[s] = ul.v;
    }
  }

  f32x4 O[4];
  #pragma unroll
  for (int ct = 0; ct < 4; ++ct) O[ct] = (f32x4){0.f, 0.f, 0.f, 0.f};
  float m_run[4] = {-INFINITY, -INFINITY, -INFINITY, -INFINITY};
  float l_run[4] = {0.f, 0.f, 0.f, 0.f};

  for (int kt = 0; kt < 32; ++kt) {
    __syncthreads();
    {
      const size_t tof = base + (size_t)kt * 2048 + tid * 8;
      const us8 a0 = *(const us8*)&Kh[tof];
      const us8 a1 = *(const us8*)&Km[tof];
      const us8 a2 = *(const us8*)&Kl[tof];
      const us8 b0 = *(const us8*)&VhT[tof];
      const us8 b1 = *(const us8*)&VmT[tof];
      const us8 b2 = *(const us8*)&VlT[tof];
      *(us8*)&Khs[klo] = a0;
      *(us8*)&Kms[klo] = a1;
      *(us8*)&Kls[klo] = a2;
      *(us8*)&Vhs[vlo] = b0;
      *(us8*)&Vms[vlo] = b1;
      *(us8*)&Vls[vlo] = b2;
    }
    __syncthreads();

    f32x4 sacc[2];
    #pragma unroll
    for (int ct = 0; ct < 2; ++ct) {
      f32x4 a = (f32x4){0.f, 0.f, 0.f, 0.f};
      #pragma unroll
      for (int s = 0; s < 2; ++s) {
        const int ko = (16 * ct + ln) * 72 + 32 * s + 8 * q;
        const bf16x8 bh = ld16B(&Khs[ko]);
        const bf16x8 bm = ld16B(&Kms[ko]);
        const bf16x8 bl = ld16B(&Kls[ko]);
        a = MFMA16(ql[s], bh, a);
        a = MFMA16(qh[s], bl, a);
        a = MFMA16(qm[s], bm, a);
        a = MFMA16(qm[s], bh, a);
        a = MFMA16(qh[s], bm, a);
        a = MFMA16(qh[s], bh, a);
      }
      sacc[ct] = a;
    }

    float rmax[4];
    #pragma unroll
    for (int r = 0; r < 4; ++r)
      rmax[r] = fmaxf(sacc[0][r], sacc[1][r]);
    #pragma unroll
    for (int mk = 1; mk <= 8; mk <<= 1) {
      #pragma unroll
      for (int r = 0; r < 4; ++r)
        rmax[r] = fmaxf(rmax[r], __shfl_xor(rmax[r], mk, 64));
    }
    float alpha[4], rsum[4];
    #pragma unroll
    for (int r = 0; r < 4; ++r) {
      const float mnew = fmaxf(m_run[r], rmax[r] * scale);
      alpha[r] = __expf(m_run[r] - mnew);
      m_run[r] = mnew;
      rsum[r] = 0.f;
    }
    #pragma unroll
    for (int ct = 0; ct < 2; ++ct) {
      #pragma unroll
      for (int r = 0; r < 4; ++r) {
        const float pv = __expf(sacc[ct][r] * scale - m_run[r]);
        rsum[r] += pv;
        Pb[(16 * w + 4 * q + r) * 36 + ln + 16 * ct] = pv;
      }
    }
    #pragma unroll
    for (int mk = 1; mk <= 8; mk <<= 1) {
      #pragma unroll
      for (int r = 0; r < 4; ++r)
        rsum[r] += __shfl_xor(rsum[r], mk, 64);
    }
    #pragma unroll
    for (int r = 0; r < 4; ++r)
      l_run[r] = l_run[r] * alpha[r] + rsum[r];

    #pragma unroll
    for (int ct = 0; ct < 4; ++ct) {
      #pragma unroll
      for (int r = 0; r < 4; ++r) O[ct][r] *= alpha[r];
    }

    bf16x8 ph, pm, pl;
    {
      const float* pp = &Pb[(16 * w + ln) * 36 + 8 * q];
      const float4 p0 = ((const float4*)pp)[0];
      const float4 p1 = ((const float4*)pp)[1];
      const float pvv[8] = {p0.x, p0.y, p0.z, p0.w, p1.x, p1.y, p1.z, p1.w};
      union { bf16x8 v; unsigned short e[8]; } uh, um, ul;
      #pragma unroll
      for (int j = 0; j < 8; ++j) {
        unsigned short h, m, l;
        split3(pvv[j], h, m, l);
        uh.e[j] = h; um.e[j] = m; ul.e[j] = l;
      }
      ph = uh.v; pm = um.v; pl = ul.v;
    }

    #pragma unroll
    for (int ct = 0; ct < 4; ++ct) {
      const int vo = (16 * ct + ln) * 40 + 8 * q;
      const bf16x8 vvh = ld16B(&Vhs[vo]);
      const bf16x8 vvm = ld16B(&Vms[vo]);
      const bf16x8 vvl = ld16B(&Vls[vo]);
      O[ct] = MFMA16(ph, vvh, O[ct]);
      O[ct] = MFMA16(ph, vvm, O[ct]);
      O[ct] = MFMA16(pm, vvh, O[ct]);
      O[ct] = MFMA16(pm, vvm, O[ct]);
      O[ct] = MFMA16(ph, vvl, O[ct]);
      O[ct] = MFMA16(pl, vvh, O[ct]);
    }
  }

  float linv[4];
  #pragma unroll
  for (int r = 0; r < 4; ++r) linv[r] = 1.0f / l_run[r];
  #pragma unroll
  for (int r = 0; r < 4; ++r) {
    const int row = i0 + 16 * w + 4 * q + r;
    float srow = 0.f;
    #pragma unroll
    for (int ct = 0; ct < 4; ++ct) {
      float* xp = X + base + (size_t)row * 64 + ln + 16 * ct;
      const float nv = *xp + O[ct][r] * linv[r];
      *xp = nv;
      srow += nv;
    }
    if (meanout) {
      #pragma unroll
      for (int mk = 1; mk <= 8; mk <<= 1)
        srow += __shfl_xor(srow, mk, 64);
      if (ln == 0) meanout[(size_t)b * DIMN + row] = srow * (1.0f / 64.0f);
    }
  }
}

// ---------------------------------------------------------------------------
// launch
// ---------------------------------------------------------------------------
extern "C" void kernel_launch(void* const* d_in, const int* in_sizes, int n_in,
                              void* d_out, int out_size, void* d_ws, size_t ws_size,
                              hipStream_t stream) {
  const float* image = (const float*)d_in[0];
  const float* WV    = (const float*)d_in[1];
  const float* WK    = (const float*)d_in[2];
  const float* WQ    = (const float*)d_in[3];
  const float* lW    = (const float*)d_in[4];
  const float* lb    = (const float*)d_in[5];
  float* out = (float*)d_out;

  float* ws = (float*)d_ws;
  const size_t NELEM = (size_t)BB * DIMN * CCH;   // 2,097,152
  const size_t NROW  = (size_t)BB * DIMN;         // 32,768

  // layout (floats): X | Q | KVsplits(3N) | Op(2N) | Mp(2R) | Lp(2R) | meanv(R)
  const size_t need_sk   = (7 * NELEM + 5 * NROW) * sizeof(float);
  const size_t need_fast = (5 * NELEM + NROW) * sizeof(float);

  if (ws_size >= need_sk) {
    float* X = ws;
    float* Q = ws + NELEM;
    unsigned short* Kh  = (unsigned short*)(ws + 2 * NELEM);
    unsigned short* Km  = Kh + NELEM;
    unsigned short* Kl  = Kh + 2 * NELEM;
    unsigned short* VhT = Kh + 3 * NELEM;
    unsigned short* VmT = Kh + 4 * NELEM;
    unsigned short* VlT = Kh + 5 * NELEM;
    float* Op    = ws + 5 * NELEM;
    float* Mp    = ws + 7 * NELEM;
    float* Lp    = Mp + 2 * NROW;
    float* meanv = Lp + 2 * NROW;
    // transposed weights live in the meanv region (12288 <= 32768 floats);
    // dead by the time k_merge_mean writes meanv.
    float* Wt    = meanv;

    k_transpose<<<dim3(DIMN / 64, BB), 256, 0, stream>>>(image, X);
    k_wtrans<<<3, 256, 0, stream>>>(WQ, WK, WV, Wt);
    k_qkv_split<<<(BB * DIMN) / 16, 256, 0, stream>>>(
        X, Wt, Q, Kh, Km, Kl, VhT, VmT, VlT);
    for (int layer = 0; layer < 8; ++layer) {
      k_attn_sk<<<1024, 256, 0, stream>>>(
          Q, Kh, Km, Kl, VhT, VmT, VlT, Mp, Lp, Op);
      if (layer < 7)
        k_qkv_merge<<<(BB * DIMN) / 16, 256, 0, stream>>>(
            X, Mp, Lp, Op, Wt, Q, Kh, Km, Kl, VhT, VmT, VlT);
    }
    k_merge_mean<<<256, 256, 0, stream>>>(X, Mp, Lp, Op, meanv);
    k_head2<<<BB, 256, 0, stream>>>(meanv, lW, lb, out);
  } else {
    // middle tier: r8 path (proven absmax 0.0)
    float* X = ws;
    float* Q = ws + NELEM;
    unsigned short* Kh  = (unsigned short*)(ws + 2 * NELEM);
    unsigned short* Km  = Kh + NELEM;
    unsigned short* Kl  = Kh + 2 * NELEM;
    unsigned short* VhT = Kh + 3 * NELEM;
    unsigned short* VmT = Kh + 4 * NELEM;
    unsigned short* VlT = Kh + 5 * NELEM;
    float* meanv = ws + 5 * NELEM;
    float* Wt    = meanv;              // same trick: dead until layer 7's attn
    (void)need_fast;

    k_transpose<<<dim3(DIMN / 64, BB), 256, 0, stream>>>(image, X);
    k_wtrans<<<3, 256, 0, stream>>>(WQ, WK, WV, Wt);
    for (int layer = 0; layer < 8; ++layer) {
      k_qkv_split<<<(BB * DIMN) / 16, 256, 0, stream>>>(
          X, Wt, Q, Kh, Km, Kl, VhT, VmT, VlT);
      k_attn_s<<<512, 256, 0, stream>>>(
          Q, Kh, Km, Kl, VhT, VmT, VlT, X, (layer == 7) ? meanv : nullptr);
    }
    k_head2<<<BB, 256, 0, stream>>>(meanv, lW, lb, out);
  }
}

// Round 2
// 888.982 us; speedup vs baseline: 1.3126x; 1.3126x over previous
//
#include <hip/hip_runtime.h>
#include <math.h>

#define BB    32
#define CCH   64
#define DIMN  1024
#define NCLS  10

typedef __attribute__((ext_vector_type(8))) short bf16x8;
typedef __attribute__((ext_vector_type(4))) float f32x4;
typedef __attribute__((ext_vector_type(4))) unsigned short us4;
typedef __attribute__((ext_vector_type(8))) unsigned short us8;

#define MFMA16(a, b, c) __builtin_amdgcn_mfma_f32_16x16x32_bf16(a, b, c, 0, 0, 0)

__device__ __forceinline__ unsigned short f2bf(float x) {
  unsigned u = __float_as_uint(x);
  unsigned r = u + 0x7fffu + ((u >> 16) & 1u);   // round-to-nearest-even
  return (unsigned short)(r >> 16);
}
__device__ __forceinline__ float bf2f(unsigned short h) {
  return __uint_as_float(((unsigned)h) << 16);
}
// x == h + m + l to ~2^-26 relative
__device__ __forceinline__ void split3(float x, unsigned short& h,
                                       unsigned short& m, unsigned short& l) {
  h = f2bf(x); float hf = bf2f(h);
  float r = x - hf;
  m = f2bf(r); float mf = bf2f(m);
  l = f2bf(r - mf);
}
__device__ __forceinline__ bf16x8 ld16B(const unsigned short* p) {
  union { us8 u; bf16x8 v; } c;
  c.u = *(const us8*)p;           // 16B-aligned -> ds_read_b128
  return c.v;
}

// ---------------------------------------------------------------------------
// 1) transpose: image (B,C,DIM) -> X (B,DIM,C)
// ---------------------------------------------------------------------------
__global__ __launch_bounds__(256) void k_transpose(const float* __restrict__ img,
                                                   float* __restrict__ X) {
  __shared__ float tile[64][65];
  const int b  = blockIdx.y;
  const int n0 = blockIdx.x * 64;
  const int tx = threadIdx.x & 63;
  const int ty = threadIdx.x >> 6;
  const float* src = img + (size_t)b * CCH * DIMN;
  #pragma unroll
  for (int c = ty; c < 64; c += 4)
    tile[c][tx] = src[(size_t)c * DIMN + n0 + tx];
  __syncthreads();
  float* dst = X + (size_t)b * DIMN * CCH;
  #pragma unroll
  for (int nn = ty; nn < 64; nn += 4)
    dst[(size_t)(n0 + nn) * CCH + tx] = tile[tx][nn];
}

// ---------------------------------------------------------------------------
// 2) QKV + per-layer pre-split (round-0 exact: W[j*64+c] is wave-coalesced):
//    Q fp32; K 3-term bf16 [t][c]; V 3-term bf16 transposed+tiled
// ---------------------------------------------------------------------------
__global__ __launch_bounds__(256) void k_qkv_split(
    const float* __restrict__ X,
    const float* __restrict__ WQ, const float* __restrict__ WK,
    const float* __restrict__ WV,
    float* __restrict__ Q,
    unsigned short* __restrict__ Kh, unsigned short* __restrict__ Km,
    unsigned short* __restrict__ Kl,
    unsigned short* __restrict__ VhT, unsigned short* __restrict__ VmT,
    unsigned short* __restrict__ VlT) {
  __shared__ float xs[16][64];
  __shared__ unsigned short vs[3][16][64];
  const int c  = threadIdx.x & 63;
  const int tg = threadIdx.x >> 6;
  const size_t t0 = (size_t)blockIdx.x * 16;
  #pragma unroll
  for (int r = tg; r < 16; r += 4)
    xs[r][c] = X[(t0 + r) * 64 + c];
  __syncthreads();
  float qa[4] = {0.f,0.f,0.f,0.f};
  float ka[4] = {0.f,0.f,0.f,0.f};
  float va[4] = {0.f,0.f,0.f,0.f};
  for (int j = 0; j < 64; ++j) {
    const float wq = WQ[j * 64 + c];
    const float wk = WK[j * 64 + c];
    const float wv = WV[j * 64 + c];
    #pragma unroll
    for (int r = 0; r < 4; ++r) {
      const float x = xs[tg * 4 + r][j];
      qa[r] = fmaf(x, wq, qa[r]);
      ka[r] = fmaf(x, wk, ka[r]);
      va[r] = fmaf(x, wv, va[r]);
    }
  }
  #pragma unroll
  for (int r = 0; r < 4; ++r) {
    const int t = tg * 4 + r;
    const size_t idx = (t0 + t) * 64 + c;
    Q[idx] = qa[r];
    unsigned short h, m, l;
    split3(ka[r], h, m, l);
    Kh[idx] = h; Km[idx] = m; Kl[idx] = l;
    split3(va[r], h, m, l);
    vs[0][t][c] = h; vs[1][t][c] = m; vs[2][t][c] = l;
  }
  __syncthreads();
  {
    const int row  = threadIdx.x >> 2;
    const int part = threadIdx.x & 3;
    const size_t bofs = (t0 >> 10) * ((size_t)DIMN * 64);
    const size_t kt   = (t0 & 1023) >> 5;
    const size_t tin  = (t0 & 31) + part * 4;
    unsigned short* dst[3] = {VhT, VmT, VlT};
    #pragma unroll
    for (int term = 0; term < 3; ++term) {
      us4 pk;
      #pragma unroll
      for (int i = 0; i < 4; ++i) pk[i] = vs[term][part * 4 + i][row];
      *(us4*)&dst[term][bofs + kt * 2048 + (size_t)row * 32 + tin] = pk;
    }
  }
}

// ---------------------------------------------------------------------------
// 2b) QKV with FUSED N-way SPLIT-K MERGE of the previous layer.
// ---------------------------------------------------------------------------
template <int NS>
__global__ __launch_bounds__(256) void k_qkv_merge(
    float* __restrict__ X,
    const float* __restrict__ Mp, const float* __restrict__ Lp,
    const float* __restrict__ Op,
    const float* __restrict__ WQ, const float* __restrict__ WK,
    const float* __restrict__ WV,
    float* __restrict__ Q,
    unsigned short* __restrict__ Kh, unsigned short* __restrict__ Km,
    unsigned short* __restrict__ Kl,
    unsigned short* __restrict__ VhT, unsigned short* __restrict__ VmT,
    unsigned short* __restrict__ VlT) {
  __shared__ float xs[16][64];
  __shared__ unsigned short vs[3][16][64];
  const int c  = threadIdx.x & 63;
  const int tg = threadIdx.x >> 6;
  const size_t t0 = (size_t)blockIdx.x * 16;
  #pragma unroll
  for (int r = tg; r < 16; r += 4) {
    const size_t grow = t0 + r;                 // global row 0..32767
    float mm = Mp[grow];
    #pragma unroll
    for (int p = 1; p < NS; ++p) mm = fmaxf(mm, Mp[(size_t)p * 32768 + grow]);
    float den = 0.f, num = 0.f;
    #pragma unroll
    for (int p = 0; p < NS; ++p) {
      const float wgt = __expf(Mp[(size_t)p * 32768 + grow] - mm);
      den = fmaf(Lp[(size_t)p * 32768 + grow], wgt, den);
      num = fmaf(Op[((size_t)p * 32768 + grow) * 64 + c], wgt, num);
    }
    const float inv = 1.0f / den;
    const float xn = X[grow * 64 + c] + num * inv;
    X[grow * 64 + c] = xn;
    xs[r][c] = xn;
  }
  __syncthreads();
  float qa[4] = {0.f,0.f,0.f,0.f};
  float ka[4] = {0.f,0.f,0.f,0.f};
  float va[4] = {0.f,0.f,0.f,0.f};
  for (int j = 0; j < 64; ++j) {
    const float wq = WQ[j * 64 + c];
    const float wk = WK[j * 64 + c];
    const float wv = WV[j * 64 + c];
    #pragma unroll
    for (int r = 0; r < 4; ++r) {
      const float x = xs[tg * 4 + r][j];
      qa[r] = fmaf(x, wq, qa[r]);
      ka[r] = fmaf(x, wk, ka[r]);
      va[r] = fmaf(x, wv, va[r]);
    }
  }
  #pragma unroll
  for (int r = 0; r < 4; ++r) {
    const int t = tg * 4 + r;
    const size_t idx = (t0 + t) * 64 + c;
    Q[idx] = qa[r];
    unsigned short h, m, l;
    split3(ka[r], h, m, l);
    Kh[idx] = h; Km[idx] = m; Kl[idx] = l;
    split3(va[r], h, m, l);
    vs[0][t][c] = h; vs[1][t][c] = m; vs[2][t][c] = l;
  }
  __syncthreads();
  {
    const int row  = threadIdx.x >> 2;
    const int part = threadIdx.x & 3;
    const size_t bofs = (t0 >> 10) * ((size_t)DIMN * 64);
    const size_t kt   = (t0 & 1023) >> 5;
    const size_t tin  = (t0 & 31) + part * 4;
    unsigned short* dst[3] = {VhT, VmT, VlT};
    #pragma unroll
    for (int term = 0; term < 3; ++term) {
      us4 pk;
      #pragma unroll
      for (int i = 0; i < 4; ++i) pk[i] = vs[term][part * 4 + i][row];
      *(us4*)&dst[term][bofs + kt * 2048 + (size_t)row * 32 + tin] = pk;
    }
  }
}

// ---------------------------------------------------------------------------
// 3) MFMA flash attention, N-way SPLIT-K. Per-tile arithmetic is round-0
//    bitwise. Structural changes vs round-0:
//      * Pb (9216 B) aliased over the Khs/Kms staging region (K dead after
//        QK^T); one extra barrier between QK^T and Pb writes makes it safe.
//        LDS 38400 -> 29184 B => 5 blocks/CU (launch_bounds 256,5).
//      * NS=4 quarters (grid 2048) so the grid can populate the 5th slot.
// ---------------------------------------------------------------------------
template <int NS>
__global__ __launch_bounds__(256, 5) void k_attn_sk(
    const float* __restrict__ Qg,
    const unsigned short* __restrict__ Kh, const unsigned short* __restrict__ Km,
    const unsigned short* __restrict__ Kl,
    const unsigned short* __restrict__ VhT, const unsigned short* __restrict__ VmT,
    const unsigned short* __restrict__ VlT,
    float* __restrict__ Mp, float* __restrict__ Lp, float* __restrict__ Op) {
  // one flat LDS block: K (3x 32x72) then V (3x 64x40); Pb aliases Khs+Kms
  __shared__ __align__(16) unsigned short lds[14592];   // 29184 B
  unsigned short* Khs = lds;             // 2304 shorts
  unsigned short* Kms = lds + 2304;
  unsigned short* Kls = lds + 4608;
  unsigned short* Vhs = lds + 6912;      // 2560 shorts each
  unsigned short* Vms = lds + 9472;
  unsigned short* Vls = lds + 12032;
  float* Pb = (float*)lds;               // 2304 floats = Khs+Kms region

  const int tid  = threadIdx.x;
  const int w    = tid >> 6;
  const int lane = tid & 63;
  const int ln   = lane & 15;
  const int q    = lane >> 4;

  // XCD-aware swizzle: batch pinned to one XCD (locality only)
  const int bid   = blockIdx.x;             // 0..512*NS-1
  const int xcd   = bid & 7;
  const int seq   = bid >> 3;               // 0..64*NS-1
  const int b     = xcd * 4 + seq / (16 * NS);   // 4 batches per XCD
  const int local = seq % (16 * NS);
  const int split = local >> 4;             // K-split index 0..NS-1
  const int i0    = (local & 15) * 64;      // Q tile

  const size_t base = (size_t)b * (DIMN * 64);
  const float scale = 0.03125f;

  const int kj = tid >> 3, kg = tid & 7;
  const int vc = tid >> 2, vg = tid & 3;
  const int klo = kj * 72 + kg * 8;
  const int vlo = vc * 40 + vg * 8;

  // ---- Q fragments: 3-term split, 2 k-chunks (once per block) --------------
  bf16x8 qh[2], qm[2], ql[2];
  {
    const int mrow = i0 + 16 * w + ln;
    const float* qp = Qg + base + (size_t)mrow * 64 + 8 * q;
    #pragma unroll
    for (int s = 0; s < 2; ++s) {
      const float4 x0 = ((const float4*)(qp + 32 * s))[0];
      const float4 x1 = ((const float4*)(qp + 32 * s))[1];
      const float xv[8] = {x0.x, x0.y, x0.z, x0.w, x1.x, x1.y, x1.z, x1.w};
      union { bf16x8 v; unsigned short e[8]; } uh, um, ul;
      #pragma unroll
      for (int j = 0; j < 8; ++j) {
        unsigned short h, m, l;
        split3(xv[j], h, m, l);
        uh.e[j] = h; um.e[j] = m; ul.e[j] = l;
      }
      qh[s] = uh.v; qm[s] = um.v; ql[s] = ul.v;
    }
  }

  f32x4 O[4];
  #pragma unroll
  for (int ct = 0; ct < 4; ++ct) O[ct] = (f32x4){0.f, 0.f, 0.f, 0.f};
  float m_run[4] = {-INFINITY, -INFINITY, -INFINITY, -INFINITY};
  float l_run[4] = {0.f, 0.f, 0.f, 0.f};

  const int TILES = 32 / NS;
  const int kt0 = split * TILES;
  for (int kt = kt0; kt < kt0 + TILES; ++kt) {
    __syncthreads();   // A: prior tile's V/Pb readers done -> safe to stage

    // ---- stage pre-split K/V tile: pure 16B copies -------------------------
    {
      const size_t tof = base + (size_t)kt * 2048 + tid * 8;  // shorts
      const us8 a0 = *(const us8*)&Kh[tof];
      const us8 a1 = *(const us8*)&Km[tof];
      const us8 a2 = *(const us8*)&Kl[tof];
      const us8 b0 = *(const us8*)&VhT[tof];
      const us8 b1 = *(const us8*)&VmT[tof];
      const us8 b2 = *(const us8*)&VlT[tof];
      *(us8*)&Khs[klo] = a0;
      *(us8*)&Kms[klo] = a1;
      *(us8*)&Kls[klo] = a2;
      *(us8*)&Vhs[vlo] = b0;
      *(us8*)&Vms[vlo] = b1;
      *(us8*)&Vls[vlo] = b2;
    }
    __syncthreads();   // B: staged tile visible

    // ---- S strip = Q . K^T via 6-product compensated MFMA (r5 order) -------
    f32x4 sacc[2];
    #pragma unroll
    for (int ct = 0; ct < 2; ++ct) {
      f32x4 a = (f32x4){0.f, 0.f, 0.f, 0.f};
      #pragma unroll
      for (int s = 0; s < 2; ++s) {
        const int ko = (16 * ct + ln) * 72 + 32 * s + 8 * q;
        const bf16x8 bh = ld16B(&Khs[ko]);
        const bf16x8 bm = ld16B(&Kms[ko]);
        const bf16x8 bl = ld16B(&Kls[ko]);
        a = MFMA16(ql[s], bh, a);
        a = MFMA16(qh[s], bl, a);
        a = MFMA16(qm[s], bm, a);
        a = MFMA16(qm[s], bh, a);
        a = MFMA16(qh[s], bm, a);
        a = MFMA16(qh[s], bh, a);
      }
      sacc[ct] = a;
    }
    __syncthreads();   // C: all waves done reading K -> Pb may overwrite it

    // ---- wave-local online softmax (round-0 identical arithmetic) ----------
    float rmax[4];
    #pragma unroll
    for (int r = 0; r < 4; ++r)
      rmax[r] = fmaxf(sacc[0][r], sacc[1][r]);
    #pragma unroll
    for (int mk = 1; mk <= 8; mk <<= 1) {
      #pragma unroll
      for (int r = 0; r < 4; ++r)
        rmax[r] = fmaxf(rmax[r], __shfl_xor(rmax[r], mk, 64));
    }
    float alpha[4], rsum[4];
    #pragma unroll
    for (int r = 0; r < 4; ++r) {
      const float mnew = fmaxf(m_run[r], rmax[r] * scale);
      alpha[r] = __expf(m_run[r] - mnew);
      m_run[r] = mnew;
      rsum[r] = 0.f;
    }
    #pragma unroll
    for (int ct = 0; ct < 2; ++ct) {
      #pragma unroll
      for (int r = 0; r < 4; ++r) {
        const float pv = __expf(sacc[ct][r] * scale - m_run[r]);
        rsum[r] += pv;
        Pb[(16 * w + 4 * q + r) * 36 + ln + 16 * ct] = pv;   // fp32, wave-local
      }
    }
    #pragma unroll
    for (int mk = 1; mk <= 8; mk <<= 1) {
      #pragma unroll
      for (int r = 0; r < 4; ++r)
        rsum[r] += __shfl_xor(rsum[r], mk, 64);
    }
    #pragma unroll
    for (int r = 0; r < 4; ++r)
      l_run[r] = l_run[r] * alpha[r] + rsum[r];

    #pragma unroll
    for (int ct = 0; ct < 4; ++ct) {
      #pragma unroll
      for (int r = 0; r < 4; ++r) O[ct][r] *= alpha[r];
    }

    // ---- P A-fragment: own rows, fp32 -> 3-term split ----------------------
    bf16x8 ph, pm, pl;
    {
      const float* pp = &Pb[(16 * w + ln) * 36 + 8 * q];
      const float4 p0 = ((const float4*)pp)[0];
      const float4 p1 = ((const float4*)pp)[1];
      const float pvv[8] = {p0.x, p0.y, p0.z, p0.w, p1.x, p1.y, p1.z, p1.w};
      union { bf16x8 v; unsigned short e[8]; } uh, um, ul;
      #pragma unroll
      for (int j = 0; j < 8; ++j) {
        unsigned short h, m, l;
        split3(pvv[j], h, m, l);
        uh.e[j] = h; um.e[j] = m; ul.e[j] = l;
      }
      ph = uh.v; pm = um.v; pl = ul.v;
    }

    // ---- O += P @ V, 6-product (r5 order) ----------------------------------
    #pragma unroll
    for (int ct = 0; ct < 4; ++ct) {
      const int vo = (16 * ct + ln) * 40 + 8 * q;
      const bf16x8 vvh = ld16B(&Vhs[vo]);
      const bf16x8 vvm = ld16B(&Vms[vo]);
      const bf16x8 vvl = ld16B(&Vls[vo]);
      O[ct] = MFMA16(ph, vvh, O[ct]);
      O[ct] = MFMA16(ph, vvm, O[ct]);
      O[ct] = MFMA16(pm, vvh, O[ct]);
      O[ct] = MFMA16(pm, vvm, O[ct]);
      O[ct] = MFMA16(ph, vvl, O[ct]);
      O[ct] = MFMA16(pl, vvh, O[ct]);
    }
  }

  // ---- epilogue: write split-K partials (m, l, raw O) ----------------------
  const size_t hofs = (size_t)split * (32 * 1024);
  #pragma unroll
  for (int r = 0; r < 4; ++r) {
    const int row = i0 + 16 * w + 4 * q + r;
    const size_t grow = hofs + (size_t)b * DIMN + row;
    #pragma unroll
    for (int ct = 0; ct < 4; ++ct)
      Op[grow * 64 + ln + 16 * ct] = O[ct][r];
    if (ln == 0) { Mp[grow] = m_run[r]; Lp[grow] = l_run[r]; }
  }
}

// ---------------------------------------------------------------------------
// 3b) final merge + channel-mean (layer 7 partials): 256 blocks x 128 tokens
// ---------------------------------------------------------------------------
template <int NS>
__global__ __launch_bounds__(256) void k_merge_mean(
    const float* __restrict__ X,
    const float* __restrict__ Mp, const float* __restrict__ Lp,
    const float* __restrict__ Op, float* __restrict__ meanv) {
  const int c  = threadIdx.x & 63;
  const int tg = threadIdx.x >> 6;
  const size_t t0 = (size_t)blockIdx.x * 128;
  for (int i = tg; i < 128; i += 4) {
    const size_t grow = t0 + i;
    float mm = Mp[grow];
    #pragma unroll
    for (int p = 1; p < NS; ++p) mm = fmaxf(mm, Mp[(size_t)p * 32768 + grow]);
    float den = 0.f, num = 0.f;
    #pragma unroll
    for (int p = 0; p < NS; ++p) {
      const float wgt = __expf(Mp[(size_t)p * 32768 + grow] - mm);
      den = fmaf(Lp[(size_t)p * 32768 + grow], wgt, den);
      num = fmaf(Op[((size_t)p * 32768 + grow) * 64 + c], wgt, num);
    }
    const float inv = 1.0f / den;
    float v = X[grow * 64 + c] + num * inv;
    #pragma unroll
    for (int off = 32; off > 0; off >>= 1)
      v += __shfl_down(v, off, 64);
    if (c == 0) meanv[grow] = v * (1.0f / 64.0f);
  }
}

// ---------------------------------------------------------------------------
// 4) head stage 2: pred[b,k] = meanv[b,:] . last_W[k,:] + last_b[k]
// ---------------------------------------------------------------------------
__global__ __launch_bounds__(256) void k_head2(
    const float* __restrict__ meanv, const float* __restrict__ lW,
    const float* __restrict__ lb, float* __restrict__ out) {
  __shared__ float red[256];
  const int b   = blockIdx.x;
  const int tid = threadIdx.x;
  float acc[NCLS];
  #pragma unroll
  for (int k = 0; k < NCLS; ++k) acc[k] = 0.f;
  for (int n = tid; n < DIMN; n += 256) {
    const float m = meanv[(size_t)b * DIMN + n];
    #pragma unroll
    for (int k = 0; k < NCLS; ++k)
      acc[k] = fmaf(m, lW[k * DIMN + n], acc[k]);
  }
  for (int k = 0; k < NCLS; ++k) {
    red[tid] = acc[k];
    __syncthreads();
    for (int s = 128; s > 0; s >>= 1) {
      if (tid < s) red[tid] += red[tid + s];
      __syncthreads();
    }
    if (tid == 0) out[b * NCLS + k] = red[0] + lb[k];
    __syncthreads();
  }
}

// ===========================================================================
// MIDDLE-TIER PATH (r8 kernel, ws >= 41 MB but < split-K need): proven 0.0
// ===========================================================================
__global__ __launch_bounds__(256) void k_attn_s(
    const float* __restrict__ Qg,
    const unsigned short* __restrict__ Kh, const unsigned short* __restrict__ Km,
    const unsigned short* __restrict__ Kl,
    const unsigned short* __restrict__ VhT, const unsigned short* __restrict__ VmT,
    const unsigned short* __restrict__ VlT,
    float* __restrict__ X, float* __restrict__ meanout) {
  __shared__ __align__(16) unsigned short Khs[32 * 72];
  __shared__ __align__(16) unsigned short Kms[32 * 72];
  __shared__ __align__(16) unsigned short Kls[32 * 72];
  __shared__ __align__(16) unsigned short Vhs[64 * 40];
  __shared__ __align__(16) unsigned short Vms[64 * 40];
  __shared__ __align__(16) unsigned short Vls[64 * 40];
  __shared__ __align__(16) float Pb[64 * 36];

  const int tid  = threadIdx.x;
  const int w    = tid >> 6;
  const int lane = tid & 63;
  const int ln   = lane & 15;
  const int q    = lane >> 4;
  const int bid = blockIdx.x;
  const int xcd = bid & 7;
  const int seq = bid >> 3;
  const int b   = xcd * 4 + (seq >> 4);
  const int i0  = (seq & 15) * 64;
  const size_t base = (size_t)b * (DIMN * 64);
  const float scale = 0.03125f;

  const int kj = tid >> 3, kg = tid & 7;
  const int vc = tid >> 2, vg = tid & 3;
  const int klo = kj * 72 + kg * 8;
  const int vlo = vc * 40 + vg * 8;

  bf16x8 qh[2], qm[2], ql[2];
  {
    const int mrow = i0 + 16 * w + ln;
    const float* qp = Qg + base + (size_t)mrow * 64 + 8 * q;
    #pragma unroll
    for (int s = 0; s < 2; ++s) {
      const float4 x0 = ((const float4*)(qp + 32 * s))[0];
      const float4 x1 = ((const float4*)(qp + 32 * s))[1];
      const float xv[8] = {x0.x, x0.y, x0.z, x0.w, x1.x, x1.y, x1.z, x1.w};
      union { bf16x8 v; unsigned short e[8]; } uh, um, ul;
      #pragma unroll
      for (int j = 0; j < 8; ++j) {
        unsigned short h, m, l;
        split3(xv[j], h, m, l);
        uh.e[j] = h; um.e[j] = m; ul.e[j] = l;
      }
      qh[s] = uh.v; qm[s] = um.v; ql[s] = ul.v;
    }
  }

  f32x4 O[4];
  #pragma unroll
  for (int ct = 0; ct < 4; ++ct) O[ct] = (f32x4){0.f, 0.f, 0.f, 0.f};
  float m_run[4] = {-INFINITY, -INFINITY, -INFINITY, -INFINITY};
  float l_run[4] = {0.f, 0.f, 0.f, 0.f};

  for (int kt = 0; kt < 32; ++kt) {
    __syncthreads();
    {
      const size_t tof = base + (size_t)kt * 2048 + tid * 8;
      const us8 a0 = *(const us8*)&Kh[tof];
      const us8 a1 = *(const us8*)&Km[tof];
      const us8 a2 = *(const us8*)&Kl[tof];
      const us8 b0 = *(const us8*)&VhT[tof];
      const us8 b1 = *(const us8*)&VmT[tof];
      const us8 b2 = *(const us8*)&VlT[tof];
      *(us8*)&Khs[klo] = a0;
      *(us8*)&Kms[klo] = a1;
      *(us8*)&Kls[klo] = a2;
      *(us8*)&Vhs[vlo] = b0;
      *(us8*)&Vms[vlo] = b1;
      *(us8*)&Vls[vlo] = b2;
    }
    __syncthreads();

    f32x4 sacc[2];
    #pragma unroll
    for (int ct = 0; ct < 2; ++ct) {
      f32x4 a = (f32x4){0.f, 0.f, 0.f, 0.f};
      #pragma unroll
      for (int s = 0; s < 2; ++s) {
        const int ko = (16 * ct + ln) * 72 + 32 * s + 8 * q;
        const bf16x8 bh = ld16B(&Khs[ko]);
        const bf16x8 bm = ld16B(&Kms[ko]);
        const bf16x8 bl = ld16B(&Kls[ko]);
        a = MFMA16(ql[s], bh, a);
        a = MFMA16(qh[s], bl, a);
        a = MFMA16(qm[s], bm, a);
        a = MFMA16(qm[s], bh, a);
        a = MFMA16(qh[s], bm, a);
        a = MFMA16(qh[s], bh, a);
      }
      sacc[ct] = a;
    }

    float rmax[4];
    #pragma unroll
    for (int r = 0; r < 4; ++r)
      rmax[r] = fmaxf(sacc[0][r], sacc[1][r]);
    #pragma unroll
    for (int mk = 1; mk <= 8; mk <<= 1) {
      #pragma unroll
      for (int r = 0; r < 4; ++r)
        rmax[r] = fmaxf(rmax[r], __shfl_xor(rmax[r], mk, 64));
    }
    float alpha[4], rsum[4];
    #pragma unroll
    for (int r = 0; r < 4; ++r) {
      const float mnew = fmaxf(m_run[r], rmax[r] * scale);
      alpha[r] = __expf(m_run[r] - mnew);
      m_run[r] = mnew;
      rsum[r] = 0.f;
    }
    #pragma unroll
    for (int ct = 0; ct < 2; ++ct) {
      #pragma unroll
      for (int r = 0; r < 4; ++r) {
        const float pv = __expf(sacc[ct][r] * scale - m_run[r]);
        rsum[r] += pv;
        Pb[(16 * w + 4 * q + r) * 36 + ln + 16 * ct] = pv;
      }
    }
    #pragma unroll
    for (int mk = 1; mk <= 8; mk <<= 1) {
      #pragma unroll
      for (int r = 0; r < 4; ++r)
        rsum[r] += __shfl_xor(rsum[r], mk, 64);
    }
    #pragma unroll
    for (int r = 0; r < 4; ++r)
      l_run[r] = l_run[r] * alpha[r] + rsum[r];

    #pragma unroll
    for (int ct = 0; ct < 4; ++ct) {
      #pragma unroll
      for (int r = 0; r < 4; ++r) O[ct][r] *= alpha[r];
    }

    bf16x8 ph, pm, pl;
    {
      const float* pp = &Pb[(16 * w + ln) * 36 + 8 * q];
      const float4 p0 = ((const float4*)pp)[0];
      const float4 p1 = ((const float4*)pp)[1];
      const float pvv[8] = {p0.x, p0.y, p0.z, p0.w, p1.x, p1.y, p1.z, p1.w};
      union { bf16x8 v; unsigned short e[8]; } uh, um, ul;
      #pragma unroll
      for (int j = 0; j < 8; ++j) {
        unsigned short h, m, l;
        split3(pvv[j], h, m, l);
        uh.e[j] = h; um.e[j] = m; ul.e[j] = l;
      }
      ph = uh.v; pm = um.v; pl = ul.v;
    }

    #pragma unroll
    for (int ct = 0; ct < 4; ++ct) {
      const int vo = (16 * ct + ln) * 40 + 8 * q;
      const bf16x8 vvh = ld16B(&Vhs[vo]);
      const bf16x8 vvm = ld16B(&Vms[vo]);
      const bf16x8 vvl = ld16B(&Vls[vo]);
      O[ct] = MFMA16(ph, vvh, O[ct]);
      O[ct] = MFMA16(ph, vvm, O[ct]);
      O[ct] = MFMA16(pm, vvh, O[ct]);
      O[ct] = MFMA16(pm, vvm, O[ct]);
      O[ct] = MFMA16(ph, vvl, O[ct]);
      O[ct] = MFMA16(pl, vvh, O[ct]);
    }
  }

  float linv[4];
  #pragma unroll
  for (int r = 0; r < 4; ++r) linv[r] = 1.0f / l_run[r];
  #pragma unroll
  for (int r = 0; r < 4; ++r) {
    const int row = i0 + 16 * w + 4 * q + r;
    float srow = 0.f;
    #pragma unroll
    for (int ct = 0; ct < 4; ++ct) {
      float* xp = X + base + (size_t)row * 64 + ln + 16 * ct;
      const float nv = *xp + O[ct][r] * linv[r];
      *xp = nv;
      srow += nv;
    }
    if (meanout) {
      #pragma unroll
      for (int mk = 1; mk <= 8; mk <<= 1)
        srow += __shfl_xor(srow, mk, 64);
      if (ln == 0) meanout[(size_t)b * DIMN + row] = srow * (1.0f / 64.0f);
    }
  }
}

// ---------------------------------------------------------------------------
// launch
// ---------------------------------------------------------------------------
extern "C" void kernel_launch(void* const* d_in, const int* in_sizes, int n_in,
                              void* d_out, int out_size, void* d_ws, size_t ws_size,
                              hipStream_t stream) {
  const float* image = (const float*)d_in[0];
  const float* WV    = (const float*)d_in[1];
  const float* WK    = (const float*)d_in[2];
  const float* WQ    = (const float*)d_in[3];
  const float* lW    = (const float*)d_in[4];
  const float* lb    = (const float*)d_in[5];
  float* out = (float*)d_out;

  float* ws = (float*)d_ws;
  const size_t NELEM = (size_t)BB * DIMN * CCH;   // 2,097,152
  const size_t NROW  = (size_t)BB * DIMN;         // 32,768

  // layout (floats): X | Q | KVsplits(3N) | Op(NS*N) | Mp(NS*R) | Lp(NS*R) | meanv(R)
  const size_t need_sk4 = (9 * NELEM + 9 * NROW) * sizeof(float);
  const size_t need_sk2 = (7 * NELEM + 5 * NROW) * sizeof(float);

  if (ws_size >= need_sk2) {
    const int NS = (ws_size >= need_sk4) ? 4 : 2;
    float* X = ws;
    float* Q = ws + NELEM;
    unsigned short* Kh  = (unsigned short*)(ws + 2 * NELEM);
    unsigned short* Km  = Kh + NELEM;
    unsigned short* Kl  = Kh + 2 * NELEM;
    unsigned short* VhT = Kh + 3 * NELEM;
    unsigned short* VmT = Kh + 4 * NELEM;
    unsigned short* VlT = Kh + 5 * NELEM;
    float* Op    = ws + 5 * NELEM;
    float* Mp    = ws + (5 + NS) * NELEM;
    float* Lp    = Mp + NS * NROW;
    float* meanv = Lp + NS * NROW;

    k_transpose<<<dim3(DIMN / 64, BB), 256, 0, stream>>>(image, X);
    k_qkv_split<<<(BB * DIMN) / 16, 256, 0, stream>>>(
        X, WQ, WK, WV, Q, Kh, Km, Kl, VhT, VmT, VlT);
    for (int layer = 0; layer < 8; ++layer) {
      if (NS == 4)
        k_attn_sk<4><<<2048, 256, 0, stream>>>(
            Q, Kh, Km, Kl, VhT, VmT, VlT, Mp, Lp, Op);
      else
        k_attn_sk<2><<<1024, 256, 0, stream>>>(
            Q, Kh, Km, Kl, VhT, VmT, VlT, Mp, Lp, Op);
      if (layer < 7) {
        if (NS == 4)
          k_qkv_merge<4><<<(BB * DIMN) / 16, 256, 0, stream>>>(
              X, Mp, Lp, Op, WQ, WK, WV, Q, Kh, Km, Kl, VhT, VmT, VlT);
        else
          k_qkv_merge<2><<<(BB * DIMN) / 16, 256, 0, stream>>>(
              X, Mp, Lp, Op, WQ, WK, WV, Q, Kh, Km, Kl, VhT, VmT, VlT);
      }
    }
    if (NS == 4)
      k_merge_mean<4><<<256, 256, 0, stream>>>(X, Mp, Lp, Op, meanv);
    else
      k_merge_mean<2><<<256, 256, 0, stream>>>(X, Mp, Lp, Op, meanv);
    k_head2<<<BB, 256, 0, stream>>>(meanv, lW, lb, out);
  } else {
    // middle tier: r8 path (proven absmax 0.0)
    float* X = ws;
    float* Q = ws + NELEM;
    unsigned short* Kh  = (unsigned short*)(ws + 2 * NELEM);
    unsigned short* Km  = Kh + NELEM;
    unsigned short* Kl  = Kh + 2 * NELEM;
    unsigned short* VhT = Kh + 3 * NELEM;
    unsigned short* VmT = Kh + 4 * NELEM;
    unsigned short* VlT = Kh + 5 * NELEM;
    float* meanv = ws + 5 * NELEM;

    k_transpose<<<dim3(DIMN / 64, BB), 256, 0, stream>>>(image, X);
    for (int layer = 0; layer < 8; ++layer) {
      k_qkv_split<<<(BB * DIMN) / 16, 256, 0, stream>>>(
          X, WQ, WK, WV, Q, Kh, Km, Kl, VhT, VmT, VlT);
      k_attn_s<<<512, 256, 0, stream>>>(
          Q, Kh, Km, Kl, VhT, VmT, VlT, X, (layer == 7) ? meanv : nullptr);
    }
    k_head2<<<BB, 256, 0, stream>>>(meanv, lW, lb, out);
  }
}

// Round 3
// 826.975 us; speedup vs baseline: 1.4111x; 1.0750x over previous
//
#include <hip/hip_runtime.h>
#include <math.h>

#define BB    32
#define CCH   64
#define DIMN  1024
#define NCLS  10

typedef __attribute__((ext_vector_type(8))) short bf16x8;
typedef __attribute__((ext_vector_type(4))) float f32x4;
typedef __attribute__((ext_vector_type(4))) unsigned short us4;
typedef __attribute__((ext_vector_type(8))) unsigned short us8;

#define MFMA16(a, b, c) __builtin_amdgcn_mfma_f32_16x16x32_bf16(a, b, c, 0, 0, 0)

__device__ __forceinline__ unsigned short f2bf(float x) {
  unsigned u = __float_as_uint(x);
  unsigned r = u + 0x7fffu + ((u >> 16) & 1u);   // round-to-nearest-even
  return (unsigned short)(r >> 16);
}
__device__ __forceinline__ float bf2f(unsigned short h) {
  return __uint_as_float(((unsigned)h) << 16);
}
// x == h + m + l to ~2^-26 relative (software path, used by qkv kernels)
__device__ __forceinline__ void split3(float x, unsigned short& h,
                                       unsigned short& m, unsigned short& l) {
  h = f2bf(x); float hf = bf2f(h);
  float r = x - hf;
  m = f2bf(r); float mf = bf2f(m);
  l = f2bf(r - mf);
}
// packed split3 of TWO floats via v_cvt_pk_bf16_f32 (hardware RNE == f2bf;
// denormal corner flushed by MFMA either way). Results pre-packed lo/hi.
__device__ __forceinline__ void split3_pk(float x0, float x1,
                                          unsigned& hp, unsigned& mp,
                                          unsigned& lp) {
  unsigned h, m, l;
  asm("v_cvt_pk_bf16_f32 %0, %1, %2" : "=v"(h) : "v"(x0), "v"(x1));
  const float h0 = __uint_as_float(h << 16);
  const float h1 = __uint_as_float(h & 0xffff0000u);
  const float r0 = x0 - h0, r1 = x1 - h1;
  asm("v_cvt_pk_bf16_f32 %0, %1, %2" : "=v"(m) : "v"(r0), "v"(r1));
  const float m0 = __uint_as_float(m << 16);
  const float m1 = __uint_as_float(m & 0xffff0000u);
  asm("v_cvt_pk_bf16_f32 %0, %1, %2" : "=v"(l) : "v"(r0 - m0), "v"(r1 - m1));
  hp = h; mp = m; lp = l;
}
// 8-element fragment split using the packed path (4x split3_pk)
__device__ __forceinline__ void split3_frag(const float* xv, bf16x8& fh,
                                            bf16x8& fm, bf16x8& fl) {
  union U { bf16x8 v; unsigned d[4]; } uh, um, ul;
  #pragma unroll
  for (int p = 0; p < 4; ++p)
    split3_pk(xv[2 * p], xv[2 * p + 1], uh.d[p], um.d[p], ul.d[p]);
  fh = uh.v; fm = um.v; fl = ul.v;
}
__device__ __forceinline__ bf16x8 ld16B(const unsigned short* p) {
  union { us8 u; bf16x8 v; } c;
  c.u = *(const us8*)p;           // 16B-aligned -> ds_read_b128
  return c.v;
}

// ---------------------------------------------------------------------------
// 1) transpose: image (B,C,DIM) -> X (B,DIM,C)
// ---------------------------------------------------------------------------
__global__ __launch_bounds__(256) void k_transpose(const float* __restrict__ img,
                                                   float* __restrict__ X) {
  __shared__ float tile[64][65];
  const int b  = blockIdx.y;
  const int n0 = blockIdx.x * 64;
  const int tx = threadIdx.x & 63;
  const int ty = threadIdx.x >> 6;
  const float* src = img + (size_t)b * CCH * DIMN;
  #pragma unroll
  for (int c = ty; c < 64; c += 4)
    tile[c][tx] = src[(size_t)c * DIMN + n0 + tx];
  __syncthreads();
  float* dst = X + (size_t)b * DIMN * CCH;
  #pragma unroll
  for (int nn = ty; nn < 64; nn += 4)
    dst[(size_t)(n0 + nn) * CCH + tx] = tile[tx][nn];
}

// ---------------------------------------------------------------------------
// 2) QKV + per-layer pre-split (round-0 exact): Q fp32; K 3-term bf16 [t][c];
//    V 3-term bf16 transposed+tiled [b][kt][c][32]
// ---------------------------------------------------------------------------
__global__ __launch_bounds__(256) void k_qkv_split(
    const float* __restrict__ X,
    const float* __restrict__ WQ, const float* __restrict__ WK,
    const float* __restrict__ WV,
    float* __restrict__ Q,
    unsigned short* __restrict__ Kh, unsigned short* __restrict__ Km,
    unsigned short* __restrict__ Kl,
    unsigned short* __restrict__ VhT, unsigned short* __restrict__ VmT,
    unsigned short* __restrict__ VlT) {
  __shared__ float xs[16][64];
  __shared__ unsigned short vs[3][16][64];
  const int c  = threadIdx.x & 63;
  const int tg = threadIdx.x >> 6;
  const size_t t0 = (size_t)blockIdx.x * 16;
  #pragma unroll
  for (int r = tg; r < 16; r += 4)
    xs[r][c] = X[(t0 + r) * 64 + c];
  __syncthreads();
  float qa[4] = {0.f,0.f,0.f,0.f};
  float ka[4] = {0.f,0.f,0.f,0.f};
  float va[4] = {0.f,0.f,0.f,0.f};
  for (int j = 0; j < 64; ++j) {
    const float wq = WQ[j * 64 + c];
    const float wk = WK[j * 64 + c];
    const float wv = WV[j * 64 + c];
    #pragma unroll
    for (int r = 0; r < 4; ++r) {
      const float x = xs[tg * 4 + r][j];
      qa[r] = fmaf(x, wq, qa[r]);
      ka[r] = fmaf(x, wk, ka[r]);
      va[r] = fmaf(x, wv, va[r]);
    }
  }
  #pragma unroll
  for (int r = 0; r < 4; ++r) {
    const int t = tg * 4 + r;
    const size_t idx = (t0 + t) * 64 + c;
    Q[idx] = qa[r];
    unsigned short h, m, l;
    split3(ka[r], h, m, l);
    Kh[idx] = h; Km[idx] = m; Kl[idx] = l;
    split3(va[r], h, m, l);
    vs[0][t][c] = h; vs[1][t][c] = m; vs[2][t][c] = l;
  }
  __syncthreads();
  {
    const int row  = threadIdx.x >> 2;
    const int part = threadIdx.x & 3;
    const size_t bofs = (t0 >> 10) * ((size_t)DIMN * 64);
    const size_t kt   = (t0 & 1023) >> 5;
    const size_t tin  = (t0 & 31) + part * 4;
    unsigned short* dst[3] = {VhT, VmT, VlT};
    #pragma unroll
    for (int term = 0; term < 3; ++term) {
      us4 pk;
      #pragma unroll
      for (int i = 0; i < 4; ++i) pk[i] = vs[term][part * 4 + i][row];
      *(us4*)&dst[term][bofs + kt * 2048 + (size_t)row * 32 + tin] = pk;
    }
  }
}

// ---------------------------------------------------------------------------
// 2b) QKV with FUSED 2-way SPLIT-K MERGE of the previous layer (round-0 exact)
// ---------------------------------------------------------------------------
__global__ __launch_bounds__(256) void k_qkv_merge(
    float* __restrict__ X,
    const float* __restrict__ Mp, const float* __restrict__ Lp,
    const float* __restrict__ Op,
    const float* __restrict__ WQ, const float* __restrict__ WK,
    const float* __restrict__ WV,
    float* __restrict__ Q,
    unsigned short* __restrict__ Kh, unsigned short* __restrict__ Km,
    unsigned short* __restrict__ Kl,
    unsigned short* __restrict__ VhT, unsigned short* __restrict__ VmT,
    unsigned short* __restrict__ VlT) {
  __shared__ float xs[16][64];
  __shared__ unsigned short vs[3][16][64];
  const int c  = threadIdx.x & 63;
  const int tg = threadIdx.x >> 6;
  const size_t t0 = (size_t)blockIdx.x * 16;
  #pragma unroll
  for (int r = tg; r < 16; r += 4) {
    const size_t grow = t0 + r;                 // global row 0..32767
    const float m0 = Mp[grow], m1 = Mp[32768 + grow];
    const float l0 = Lp[grow], l1 = Lp[32768 + grow];
    const float mm = fmaxf(m0, m1);
    const float w0 = __expf(m0 - mm), w1 = __expf(m1 - mm);
    const float inv = 1.0f / (l0 * w0 + l1 * w1);
    const float o0 = Op[grow * 64 + c];
    const float o1 = Op[(size_t)2097152 + grow * 64 + c];
    const float xn = X[grow * 64 + c] + (o0 * w0 + o1 * w1) * inv;
    X[grow * 64 + c] = xn;
    xs[r][c] = xn;
  }
  __syncthreads();
  float qa[4] = {0.f,0.f,0.f,0.f};
  float ka[4] = {0.f,0.f,0.f,0.f};
  float va[4] = {0.f,0.f,0.f,0.f};
  for (int j = 0; j < 64; ++j) {
    const float wq = WQ[j * 64 + c];
    const float wk = WK[j * 64 + c];
    const float wv = WV[j * 64 + c];
    #pragma unroll
    for (int r = 0; r < 4; ++r) {
      const float x = xs[tg * 4 + r][j];
      qa[r] = fmaf(x, wq, qa[r]);
      ka[r] = fmaf(x, wk, ka[r]);
      va[r] = fmaf(x, wv, va[r]);
    }
  }
  #pragma unroll
  for (int r = 0; r < 4; ++r) {
    const int t = tg * 4 + r;
    const size_t idx = (t0 + t) * 64 + c;
    Q[idx] = qa[r];
    unsigned short h, m, l;
    split3(ka[r], h, m, l);
    Kh[idx] = h; Km[idx] = m; Kl[idx] = l;
    split3(va[r], h, m, l);
    vs[0][t][c] = h; vs[1][t][c] = m; vs[2][t][c] = l;
  }
  __syncthreads();
  {
    const int row  = threadIdx.x >> 2;
    const int part = threadIdx.x & 3;
    const size_t bofs = (t0 >> 10) * ((size_t)DIMN * 64);
    const size_t kt   = (t0 & 1023) >> 5;
    const size_t tin  = (t0 & 31) + part * 4;
    unsigned short* dst[3] = {VhT, VmT, VlT};
    #pragma unroll
    for (int term = 0; term < 3; ++term) {
      us4 pk;
      #pragma unroll
      for (int i = 0; i < 4; ++i) pk[i] = vs[term][part * 4 + i][row];
      *(us4*)&dst[term][bofs + kt * 2048 + (size_t)row * 32 + tin] = pk;
    }
  }
}

// ---------------------------------------------------------------------------
// 3) MFMA flash attention, SPLIT-K (2 halves). Round-0 structure exactly
//    (grid 1024, 4 blocks/CU, separate Pb, 2 barriers/tile); single change:
//    Q- and P-fragment 3-term splits use packed v_cvt_pk_bf16_f32
//    (bitwise-identical rounding, ~60 fewer VALU instr per wave-tile).
// ---------------------------------------------------------------------------
__global__ __launch_bounds__(256, 4) void k_attn_sk(
    const float* __restrict__ Qg,
    const unsigned short* __restrict__ Kh, const unsigned short* __restrict__ Km,
    const unsigned short* __restrict__ Kl,
    const unsigned short* __restrict__ VhT, const unsigned short* __restrict__ VmT,
    const unsigned short* __restrict__ VlT,
    float* __restrict__ Mp, float* __restrict__ Lp, float* __restrict__ Op) {
  __shared__ __align__(16) unsigned short Khs[32 * 72];
  __shared__ __align__(16) unsigned short Kms[32 * 72];
  __shared__ __align__(16) unsigned short Kls[32 * 72];
  __shared__ __align__(16) unsigned short Vhs[64 * 40];   // V^T: [c][j]
  __shared__ __align__(16) unsigned short Vms[64 * 40];
  __shared__ __align__(16) unsigned short Vls[64 * 40];
  __shared__ __align__(16) float Pb[64 * 36];             // fp32 P round-trip

  const int tid  = threadIdx.x;
  const int w    = tid >> 6;
  const int lane = tid & 63;
  const int ln   = lane & 15;
  const int q    = lane >> 4;

  // XCD-aware swizzle: 1024 blocks; batch pinned to one XCD (locality only)
  const int bid   = blockIdx.x;            // 0..1023
  const int xcd   = bid & 7;
  const int seq   = bid >> 3;              // 0..127
  const int b     = xcd * 4 + (seq >> 5);  // 4 batches per XCD
  const int local = seq & 31;
  const int half  = local >> 4;            // K-split half
  const int i0    = (local & 15) * 64;     // Q tile

  const size_t base = (size_t)b * (DIMN * 64);
  const float scale = 0.03125f;

  const int kj = tid >> 3, kg = tid & 7;
  const int vc = tid >> 2, vg = tid & 3;
  const int klo = kj * 72 + kg * 8;
  const int vlo = vc * 40 + vg * 8;

  // ---- Q fragments: 3-term split (packed), 2 k-chunks (once per block) -----
  bf16x8 qh[2], qm[2], ql[2];
  {
    const int mrow = i0 + 16 * w + ln;
    const float* qp = Qg + base + (size_t)mrow * 64 + 8 * q;
    #pragma unroll
    for (int s = 0; s < 2; ++s) {
      const float4 x0 = ((const float4*)(qp + 32 * s))[0];
      const float4 x1 = ((const float4*)(qp + 32 * s))[1];
      const float xv[8] = {x0.x, x0.y, x0.z, x0.w, x1.x, x1.y, x1.z, x1.w};
      split3_frag(xv, qh[s], qm[s], ql[s]);
    }
  }

  f32x4 O[4];
  #pragma unroll
  for (int ct = 0; ct < 4; ++ct) O[ct] = (f32x4){0.f, 0.f, 0.f, 0.f};
  float m_run[4] = {-INFINITY, -INFINITY, -INFINITY, -INFINITY};
  float l_run[4] = {0.f, 0.f, 0.f, 0.f};

  const int kt0 = half * 16;
  for (int kt = kt0; kt < kt0 + 16; ++kt) {
    __syncthreads();   // previous iteration's K/V readers done

    // ---- stage pre-split K/V tile: pure 16B copies -------------------------
    {
      const size_t tof = base + (size_t)kt * 2048 + tid * 8;  // shorts
      const us8 a0 = *(const us8*)&Kh[tof];
      const us8 a1 = *(const us8*)&Km[tof];
      const us8 a2 = *(const us8*)&Kl[tof];
      const us8 b0 = *(const us8*)&VhT[tof];
      const us8 b1 = *(const us8*)&VmT[tof];
      const us8 b2 = *(const us8*)&VlT[tof];
      *(us8*)&Khs[klo] = a0;
      *(us8*)&Kms[klo] = a1;
      *(us8*)&Kls[klo] = a2;
      *(us8*)&Vhs[vlo] = b0;
      *(us8*)&Vms[vlo] = b1;
      *(us8*)&Vls[vlo] = b2;
    }
    __syncthreads();

    // ---- S strip = Q . K^T via 6-product compensated MFMA (r5 order) -------
    f32x4 sacc[2];
    #pragma unroll
    for (int ct = 0; ct < 2; ++ct) {
      f32x4 a = (f32x4){0.f, 0.f, 0.f, 0.f};
      #pragma unroll
      for (int s = 0; s < 2; ++s) {
        const int ko = (16 * ct + ln) * 72 + 32 * s + 8 * q;
        const bf16x8 bh = ld16B(&Khs[ko]);
        const bf16x8 bm = ld16B(&Kms[ko]);
        const bf16x8 bl = ld16B(&Kls[ko]);
        a = MFMA16(ql[s], bh, a);
        a = MFMA16(qh[s], bl, a);
        a = MFMA16(qm[s], bm, a);
        a = MFMA16(qm[s], bh, a);
        a = MFMA16(qh[s], bm, a);
        a = MFMA16(qh[s], bh, a);
      }
      sacc[ct] = a;
    }

    // ---- wave-local online softmax (round-0 identical arithmetic) ----------
    float rmax[4];
    #pragma unroll
    for (int r = 0; r < 4; ++r)
      rmax[r] = fmaxf(sacc[0][r], sacc[1][r]);
    #pragma unroll
    for (int mk = 1; mk <= 8; mk <<= 1) {
      #pragma unroll
      for (int r = 0; r < 4; ++r)
        rmax[r] = fmaxf(rmax[r], __shfl_xor(rmax[r], mk, 64));
    }
    float alpha[4], rsum[4];
    #pragma unroll
    for (int r = 0; r < 4; ++r) {
      const float mnew = fmaxf(m_run[r], rmax[r] * scale);
      alpha[r] = __expf(m_run[r] - mnew);
      m_run[r] = mnew;
      rsum[r] = 0.f;
    }
    #pragma unroll
    for (int ct = 0; ct < 2; ++ct) {
      #pragma unroll
      for (int r = 0; r < 4; ++r) {
        const float pv = __expf(sacc[ct][r] * scale - m_run[r]);
        rsum[r] += pv;
        Pb[(16 * w + 4 * q + r) * 36 + ln + 16 * ct] = pv;   // fp32, wave-local
      }
    }
    #pragma unroll
    for (int mk = 1; mk <= 8; mk <<= 1) {
      #pragma unroll
      for (int r = 0; r < 4; ++r)
        rsum[r] += __shfl_xor(rsum[r], mk, 64);
    }
    #pragma unroll
    for (int r = 0; r < 4; ++r)
      l_run[r] = l_run[r] * alpha[r] + rsum[r];

    #pragma unroll
    for (int ct = 0; ct < 4; ++ct) {
      #pragma unroll
      for (int r = 0; r < 4; ++r) O[ct][r] *= alpha[r];
    }

    // ---- P A-fragment: own rows, fp32 -> 3-term split (packed) -------------
    bf16x8 ph, pm, pl;
    {
      const float* pp = &Pb[(16 * w + ln) * 36 + 8 * q];
      const float4 p0 = ((const float4*)pp)[0];
      const float4 p1 = ((const float4*)pp)[1];
      const float pvv[8] = {p0.x, p0.y, p0.z, p0.w, p1.x, p1.y, p1.z, p1.w};
      split3_frag(pvv, ph, pm, pl);
    }

    // ---- O += P @ V, 6-product (r5 order) ----------------------------------
    #pragma unroll
    for (int ct = 0; ct < 4; ++ct) {
      const int vo = (16 * ct + ln) * 40 + 8 * q;
      const bf16x8 vvh = ld16B(&Vhs[vo]);
      const bf16x8 vvm = ld16B(&Vms[vo]);
      const bf16x8 vvl = ld16B(&Vls[vo]);
      O[ct] = MFMA16(ph, vvh, O[ct]);
      O[ct] = MFMA16(ph, vvm, O[ct]);
      O[ct] = MFMA16(pm, vvh, O[ct]);
      O[ct] = MFMA16(pm, vvm, O[ct]);
      O[ct] = MFMA16(ph, vvl, O[ct]);
      O[ct] = MFMA16(pl, vvh, O[ct]);
    }
  }

  // ---- epilogue: write split-K partials (m, l, raw O) ----------------------
  const size_t hofs = (size_t)half * (32 * 1024);
  #pragma unroll
  for (int r = 0; r < 4; ++r) {
    const int row = i0 + 16 * w + 4 * q + r;
    const size_t grow = hofs + (size_t)b * DIMN + row;
    #pragma unroll
    for (int ct = 0; ct < 4; ++ct)
      Op[grow * 64 + ln + 16 * ct] = O[ct][r];
    if (ln == 0) { Mp[grow] = m_run[r]; Lp[grow] = l_run[r]; }
  }
}

// ---------------------------------------------------------------------------
// 3b) final merge + channel-mean (layer 7 partials): 256 blocks x 128 tokens
// ---------------------------------------------------------------------------
__global__ __launch_bounds__(256) void k_merge_mean(
    const float* __restrict__ X,
    const float* __restrict__ Mp, const float* __restrict__ Lp,
    const float* __restrict__ Op, float* __restrict__ meanv) {
  const int c  = threadIdx.x & 63;
  const int tg = threadIdx.x >> 6;
  const size_t t0 = (size_t)blockIdx.x * 128;
  for (int i = tg; i < 128; i += 4) {
    const size_t grow = t0 + i;
    const float m0 = Mp[grow], m1 = Mp[32768 + grow];
    const float l0 = Lp[grow], l1 = Lp[32768 + grow];
    const float mm = fmaxf(m0, m1);
    const float w0 = __expf(m0 - mm), w1 = __expf(m1 - mm);
    const float inv = 1.0f / (l0 * w0 + l1 * w1);
    const float o0 = Op[grow * 64 + c];
    const float o1 = Op[(size_t)2097152 + grow * 64 + c];
    float v = X[grow * 64 + c] + (o0 * w0 + o1 * w1) * inv;
    #pragma unroll
    for (int off = 32; off > 0; off >>= 1)
      v += __shfl_down(v, off, 64);
    if (c == 0) meanv[grow] = v * (1.0f / 64.0f);
  }
}

// ---------------------------------------------------------------------------
// 4) head stage 2: pred[b,k] = meanv[b,:] . last_W[k,:] + last_b[k]
// ---------------------------------------------------------------------------
__global__ __launch_bounds__(256) void k_head2(
    const float* __restrict__ meanv, const float* __restrict__ lW,
    const float* __restrict__ lb, float* __restrict__ out) {
  __shared__ float red[256];
  const int b   = blockIdx.x;
  const int tid = threadIdx.x;
  float acc[NCLS];
  #pragma unroll
  for (int k = 0; k < NCLS; ++k) acc[k] = 0.f;
  for (int n = tid; n < DIMN; n += 256) {
    const float m = meanv[(size_t)b * DIMN + n];
    #pragma unroll
    for (int k = 0; k < NCLS; ++k)
      acc[k] = fmaf(m, lW[k * DIMN + n], acc[k]);
  }
  for (int k = 0; k < NCLS; ++k) {
    red[tid] = acc[k];
    __syncthreads();
    for (int s = 128; s > 0; s >>= 1) {
      if (tid < s) red[tid] += red[tid + s];
      __syncthreads();
    }
    if (tid == 0) out[b * NCLS + k] = red[0] + lb[k];
    __syncthreads();
  }
}

// ===========================================================================
// MIDDLE-TIER PATH (r8 kernel, ws >= 41 MB but < split-K need)
// ===========================================================================
__global__ __launch_bounds__(256) void k_attn_s(
    const float* __restrict__ Qg,
    const unsigned short* __restrict__ Kh, const unsigned short* __restrict__ Km,
    const unsigned short* __restrict__ Kl,
    const unsigned short* __restrict__ VhT, const unsigned short* __restrict__ VmT,
    const unsigned short* __restrict__ VlT,
    float* __restrict__ X, float* __restrict__ meanout) {
  __shared__ __align__(16) unsigned short Khs[32 * 72];
  __shared__ __align__(16) unsigned short Kms[32 * 72];
  __shared__ __align__(16) unsigned short Kls[32 * 72];
  __shared__ __align__(16) unsigned short Vhs[64 * 40];
  __shared__ __align__(16) unsigned short Vms[64 * 40];
  __shared__ __align__(16) unsigned short Vls[64 * 40];
  __shared__ __align__(16) float Pb[64 * 36];

  const int tid  = threadIdx.x;
  const int w    = tid >> 6;
  const int lane = tid & 63;
  const int ln   = lane & 15;
  const int q    = lane >> 4;
  const int bid = blockIdx.x;
  const int xcd = bid & 7;
  const int seq = bid >> 3;
  const int b   = xcd * 4 + (seq >> 4);
  const int i0  = (seq & 15) * 64;
  const size_t base = (size_t)b * (DIMN * 64);
  const float scale = 0.03125f;

  const int kj = tid >> 3, kg = tid & 7;
  const int vc = tid >> 2, vg = tid & 3;
  const int klo = kj * 72 + kg * 8;
  const int vlo = vc * 40 + vg * 8;

  bf16x8 qh[2], qm[2], ql[2];
  {
    const int mrow = i0 + 16 * w + ln;
    const float* qp = Qg + base + (size_t)mrow * 64 + 8 * q;
    #pragma unroll
    for (int s = 0; s < 2; ++s) {
      const float4 x0 = ((const float4*)(qp + 32 * s))[0];
      const float4 x1 = ((const float4*)(qp + 32 * s))[1];
      const float xv[8] = {x0.x, x0.y, x0.z, x0.w, x1.x, x1.y, x1.z, x1.w};
      split3_frag(xv, qh[s], qm[s], ql[s]);
    }
  }

  f32x4 O[4];
  #pragma unroll
  for (int ct = 0; ct < 4; ++ct) O[ct] = (f32x4){0.f, 0.f, 0.f, 0.f};
  float m_run[4] = {-INFINITY, -INFINITY, -INFINITY, -INFINITY};
  float l_run[4] = {0.f, 0.f, 0.f, 0.f};

  for (int kt = 0; kt < 32; ++kt) {
    __syncthreads();
    {
      const size_t tof = base + (size_t)kt * 2048 + tid * 8;
      const us8 a0 = *(const us8*)&Kh[tof];
      const us8 a1 = *(const us8*)&Km[tof];
      const us8 a2 = *(const us8*)&Kl[tof];
      const us8 b0 = *(const us8*)&VhT[tof];
      const us8 b1 = *(const us8*)&VmT[tof];
      const us8 b2 = *(const us8*)&VlT[tof];
      *(us8*)&Khs[klo] = a0;
      *(us8*)&Kms[klo] = a1;
      *(us8*)&Kls[klo] = a2;
      *(us8*)&Vhs[vlo] = b0;
      *(us8*)&Vms[vlo] = b1;
      *(us8*)&Vls[vlo] = b2;
    }
    __syncthreads();

    f32x4 sacc[2];
    #pragma unroll
    for (int ct = 0; ct < 2; ++ct) {
      f32x4 a = (f32x4){0.f, 0.f, 0.f, 0.f};
      #pragma unroll
      for (int s = 0; s < 2; ++s) {
        const int ko = (16 * ct + ln) * 72 + 32 * s + 8 * q;
        const bf16x8 bh = ld16B(&Khs[ko]);
        const bf16x8 bm = ld16B(&Kms[ko]);
        const bf16x8 bl = ld16B(&Kls[ko]);
        a = MFMA16(ql[s], bh, a);
        a = MFMA16(qh[s], bl, a);
        a = MFMA16(qm[s], bm, a);
        a = MFMA16(qm[s], bh, a);
        a = MFMA16(qh[s], bm, a);
        a = MFMA16(qh[s], bh, a);
      }
      sacc[ct] = a;
    }

    float rmax[4];
    #pragma unroll
    for (int r = 0; r < 4; ++r)
      rmax[r] = fmaxf(sacc[0][r], sacc[1][r]);
    #pragma unroll
    for (int mk = 1; mk <= 8; mk <<= 1) {
      #pragma unroll
      for (int r = 0; r < 4; ++r)
        rmax[r] = fmaxf(rmax[r], __shfl_xor(rmax[r], mk, 64));
    }
    float alpha[4], rsum[4];
    #pragma unroll
    for (int r = 0; r < 4; ++r) {
      const float mnew = fmaxf(m_run[r], rmax[r] * scale);
      alpha[r] = __expf(m_run[r] - mnew);
      m_run[r] = mnew;
      rsum[r] = 0.f;
    }
    #pragma unroll
    for (int ct = 0; ct < 2; ++ct) {
      #pragma unroll
      for (int r = 0; r < 4; ++r) {
        const float pv = __expf(sacc[ct][r] * scale - m_run[r]);
        rsum[r] += pv;
        Pb[(16 * w + 4 * q + r) * 36 + ln + 16 * ct] = pv;
      }
    }
    #pragma unroll
    for (int mk = 1; mk <= 8; mk <<= 1) {
      #pragma unroll
      for (int r = 0; r < 4; ++r)
        rsum[r] += __shfl_xor(rsum[r], mk, 64);
    }
    #pragma unroll
    for (int r = 0; r < 4; ++r)
      l_run[r] = l_run[r] * alpha[r] + rsum[r];

    #pragma unroll
    for (int ct = 0; ct < 4; ++ct) {
      #pragma unroll
      for (int r = 0; r < 4; ++r) O[ct][r] *= alpha[r];
    }

    bf16x8 ph, pm, pl;
    {
      const float* pp = &Pb[(16 * w + ln) * 36 + 8 * q];
      const float4 p0 = ((const float4*)pp)[0];
      const float4 p1 = ((const float4*)pp)[1];
      const float pvv[8] = {p0.x, p0.y, p0.z, p0.w, p1.x, p1.y, p1.z, p1.w};
      split3_frag(pvv, ph, pm, pl);
    }

    #pragma unroll
    for (int ct = 0; ct < 4; ++ct) {
      const int vo = (16 * ct + ln) * 40 + 8 * q;
      const bf16x8 vvh = ld16B(&Vhs[vo]);
      const bf16x8 vvm = ld16B(&Vms[vo]);
      const bf16x8 vvl = ld16B(&Vls[vo]);
      O[ct] = MFMA16(ph, vvh, O[ct]);
      O[ct] = MFMA16(ph, vvm, O[ct]);
      O[ct] = MFMA16(pm, vvh, O[ct]);
      O[ct] = MFMA16(pm, vvm, O[ct]);
      O[ct] = MFMA16(ph, vvl, O[ct]);
      O[ct] = MFMA16(pl, vvh, O[ct]);
    }
  }

  float linv[4];
  #pragma unroll
  for (int r = 0; r < 4; ++r) linv[r] = 1.0f / l_run[r];
  #pragma unroll
  for (int r = 0; r < 4; ++r) {
    const int row = i0 + 16 * w + 4 * q + r;
    float srow = 0.f;
    #pragma unroll
    for (int ct = 0; ct < 4; ++ct) {
      float* xp = X + base + (size_t)row * 64 + ln + 16 * ct;
      const float nv = *xp + O[ct][r] * linv[r];
      *xp = nv;
      srow += nv;
    }
    if (meanout) {
      #pragma unroll
      for (int mk = 1; mk <= 8; mk <<= 1)
        srow += __shfl_xor(srow, mk, 64);
      if (ln == 0) meanout[(size_t)b * DIMN + row] = srow * (1.0f / 64.0f);
    }
  }
}

// ---------------------------------------------------------------------------
// launch
// ---------------------------------------------------------------------------
extern "C" void kernel_launch(void* const* d_in, const int* in_sizes, int n_in,
                              void* d_out, int out_size, void* d_ws, size_t ws_size,
                              hipStream_t stream) {
  const float* image = (const float*)d_in[0];
  const float* WV    = (const float*)d_in[1];
  const float* WK    = (const float*)d_in[2];
  const float* WQ    = (const float*)d_in[3];
  const float* lW    = (const float*)d_in[4];
  const float* lb    = (const float*)d_in[5];
  float* out = (float*)d_out;

  float* ws = (float*)d_ws;
  const size_t NELEM = (size_t)BB * DIMN * CCH;   // 2,097,152
  const size_t NROW  = (size_t)BB * DIMN;         // 32,768

  // layout (floats): X | Q | KVsplits(3N) | Op(2N) | Mp(2R) | Lp(2R) | meanv(R)
  const size_t need_sk   = (7 * NELEM + 5 * NROW) * sizeof(float);
  const size_t need_fast = (5 * NELEM + NROW) * sizeof(float);

  if (ws_size >= need_sk) {
    float* X = ws;
    float* Q = ws + NELEM;
    unsigned short* Kh  = (unsigned short*)(ws + 2 * NELEM);
    unsigned short* Km  = Kh + NELEM;
    unsigned short* Kl  = Kh + 2 * NELEM;
    unsigned short* VhT = Kh + 3 * NELEM;
    unsigned short* VmT = Kh + 4 * NELEM;
    unsigned short* VlT = Kh + 5 * NELEM;
    float* Op    = ws + 5 * NELEM;
    float* Mp    = ws + 7 * NELEM;
    float* Lp    = Mp + 2 * NROW;
    float* meanv = Lp + 2 * NROW;

    k_transpose<<<dim3(DIMN / 64, BB), 256, 0, stream>>>(image, X);
    k_qkv_split<<<(BB * DIMN) / 16, 256, 0, stream>>>(
        X, WQ, WK, WV, Q, Kh, Km, Kl, VhT, VmT, VlT);
    for (int layer = 0; layer < 8; ++layer) {
      k_attn_sk<<<1024, 256, 0, stream>>>(
          Q, Kh, Km, Kl, VhT, VmT, VlT, Mp, Lp, Op);
      if (layer < 7)
        k_qkv_merge<<<(BB * DIMN) / 16, 256, 0, stream>>>(
            X, Mp, Lp, Op, WQ, WK, WV, Q, Kh, Km, Kl, VhT, VmT, VlT);
    }
    k_merge_mean<<<256, 256, 0, stream>>>(X, Mp, Lp, Op, meanv);
    k_head2<<<BB, 256, 0, stream>>>(meanv, lW, lb, out);
  } else {
    // middle tier: r8 path
    float* X = ws;
    float* Q = ws + NELEM;
    unsigned short* Kh  = (unsigned short*)(ws + 2 * NELEM);
    unsigned short* Km  = Kh + NELEM;
    unsigned short* Kl  = Kh + 2 * NELEM;
    unsigned short* VhT = Kh + 3 * NELEM;
    unsigned short* VmT = Kh + 4 * NELEM;
    unsigned short* VlT = Kh + 5 * NELEM;
    float* meanv = ws + 5 * NELEM;
    (void)need_fast;

    k_transpose<<<dim3(DIMN / 64, BB), 256, 0, stream>>>(image, X);
    for (int layer = 0; layer < 8; ++layer) {
      k_qkv_split<<<(BB * DIMN) / 16, 256, 0, stream>>>(
          X, WQ, WK, WV, Q, Kh, Km, Kl, VhT, VmT, VlT);
      k_attn_s<<<512, 256, 0, stream>>>(
          Q, Kh, Km, Kl, VhT, VmT, VlT, X, (layer == 7) ? meanv : nullptr);
    }
    k_head2<<<BB, 256, 0, stream>>>(meanv, lW, lb, out);
  }
}

// Round 4
// 716.402 us; speedup vs baseline: 1.6289x; 1.1543x over previous
//
#include <hip/hip_runtime.h>
#include <math.h>

#define BB    32
#define CCH   64
#define DIMN  1024
#define NCLS  10

typedef __attribute__((ext_vector_type(8))) short bf16x8;
typedef __attribute__((ext_vector_type(4))) float f32x4;
typedef __attribute__((ext_vector_type(4))) unsigned short us4;
typedef __attribute__((ext_vector_type(8))) unsigned short us8;

#define MFMA16(a, b, c) __builtin_amdgcn_mfma_f32_16x16x32_bf16(a, b, c, 0, 0, 0)

__device__ __forceinline__ unsigned short f2bf(float x) {
  unsigned u = __float_as_uint(x);
  unsigned r = u + 0x7fffu + ((u >> 16) & 1u);   // round-to-nearest-even
  return (unsigned short)(r >> 16);
}
__device__ __forceinline__ float bf2f(unsigned short h) {
  return __uint_as_float(((unsigned)h) << 16);
}
// x == h + m + l to ~2^-26 relative (software path, used by qkv kernels)
__device__ __forceinline__ void split3(float x, unsigned short& h,
                                       unsigned short& m, unsigned short& l) {
  h = f2bf(x); float hf = bf2f(h);
  float r = x - hf;
  m = f2bf(r); float mf = bf2f(m);
  l = f2bf(r - mf);
}
// packed split3 of TWO floats via v_cvt_pk_bf16_f32 (hardware RNE == f2bf)
__device__ __forceinline__ void split3_pk(float x0, float x1,
                                          unsigned& hp, unsigned& mp,
                                          unsigned& lp) {
  unsigned h, m, l;
  asm("v_cvt_pk_bf16_f32 %0, %1, %2" : "=v"(h) : "v"(x0), "v"(x1));
  const float h0 = __uint_as_float(h << 16);
  const float h1 = __uint_as_float(h & 0xffff0000u);
  const float r0 = x0 - h0, r1 = x1 - h1;
  asm("v_cvt_pk_bf16_f32 %0, %1, %2" : "=v"(m) : "v"(r0), "v"(r1));
  const float m0 = __uint_as_float(m << 16);
  const float m1 = __uint_as_float(m & 0xffff0000u);
  asm("v_cvt_pk_bf16_f32 %0, %1, %2" : "=v"(l) : "v"(r0 - m0), "v"(r1 - m1));
  hp = h; mp = m; lp = l;
}
// 8-element fragment split using the packed path (4x split3_pk)
__device__ __forceinline__ void split3_frag(const float* xv, bf16x8& fh,
                                            bf16x8& fm, bf16x8& fl) {
  union U { bf16x8 v; unsigned d[4]; } uh, um, ul;
  #pragma unroll
  for (int p = 0; p < 4; ++p)
    split3_pk(xv[2 * p], xv[2 * p + 1], uh.d[p], um.d[p], ul.d[p]);
  fh = uh.v; fm = um.v; fl = ul.v;
}
__device__ __forceinline__ bf16x8 ld16B(const unsigned short* p) {
  union { us8 u; bf16x8 v; } c;
  c.u = *(const us8*)p;           // 16B-aligned -> ds_read_b128
  return c.v;
}

// ---------------------------------------------------------------------------
// 1) transpose: image (B,C,DIM) -> X (B,DIM,C)
// ---------------------------------------------------------------------------
__global__ __launch_bounds__(256) void k_transpose(const float* __restrict__ img,
                                                   float* __restrict__ X) {
  __shared__ float tile[64][65];
  const int b  = blockIdx.y;
  const int n0 = blockIdx.x * 64;
  const int tx = threadIdx.x & 63;
  const int ty = threadIdx.x >> 6;
  const float* src = img + (size_t)b * CCH * DIMN;
  #pragma unroll
  for (int c = ty; c < 64; c += 4)
    tile[c][tx] = src[(size_t)c * DIMN + n0 + tx];
  __syncthreads();
  float* dst = X + (size_t)b * DIMN * CCH;
  #pragma unroll
  for (int nn = ty; nn < 64; nn += 4)
    dst[(size_t)(n0 + nn) * CCH + tx] = tile[tx][nn];
}

// ---------------------------------------------------------------------------
// 2) QKV + per-layer pre-split: Q fp32; K 3-term bf16 [t][c];
//    V 3-term bf16 transposed+tiled [b][kt][c][32], columns sigma-permuted:
//    token T (bits c,h1h0,i1i0) -> col (h1h0,c,i1i0) so attention's PV
//    A-fragment is the lane's own P values in-order (no redistribution).
// ---------------------------------------------------------------------------
__global__ __launch_bounds__(256) void k_qkv_split(
    const float* __restrict__ X,
    const float* __restrict__ WQ, const float* __restrict__ WK,
    const float* __restrict__ WV,
    float* __restrict__ Q,
    unsigned short* __restrict__ Kh, unsigned short* __restrict__ Km,
    unsigned short* __restrict__ Kl,
    unsigned short* __restrict__ VhT, unsigned short* __restrict__ VmT,
    unsigned short* __restrict__ VlT) {
  __shared__ float xs[16][64];
  __shared__ unsigned short vs[3][16][64];
  const int c  = threadIdx.x & 63;
  const int tg = threadIdx.x >> 6;
  const size_t t0 = (size_t)blockIdx.x * 16;
  #pragma unroll
  for (int r = tg; r < 16; r += 4)
    xs[r][c] = X[(t0 + r) * 64 + c];
  __syncthreads();
  float qa[4] = {0.f,0.f,0.f,0.f};
  float ka[4] = {0.f,0.f,0.f,0.f};
  float va[4] = {0.f,0.f,0.f,0.f};
  for (int j = 0; j < 64; ++j) {
    const float wq = WQ[j * 64 + c];
    const float wk = WK[j * 64 + c];
    const float wv = WV[j * 64 + c];
    #pragma unroll
    for (int r = 0; r < 4; ++r) {
      const float x = xs[tg * 4 + r][j];
      qa[r] = fmaf(x, wq, qa[r]);
      ka[r] = fmaf(x, wk, ka[r]);
      va[r] = fmaf(x, wv, va[r]);
    }
  }
  #pragma unroll
  for (int r = 0; r < 4; ++r) {
    const int t = tg * 4 + r;
    const size_t idx = (t0 + t) * 64 + c;
    Q[idx] = qa[r];
    unsigned short h, m, l;
    split3(ka[r], h, m, l);
    Kh[idx] = h; Km[idx] = m; Kl[idx] = l;
    split3(va[r], h, m, l);
    vs[0][t][c] = h; vs[1][t][c] = m; vs[2][t][c] = l;
  }
  __syncthreads();
  {
    const int row  = threadIdx.x >> 2;
    const int part = threadIdx.x & 3;
    const size_t bofs = (t0 >> 10) * ((size_t)DIMN * 64);
    const size_t kt   = (t0 & 1023) >> 5;
    const size_t tin  = (size_t)part * 8 + ((t0 & 31) >> 2);   // sigma permute
    unsigned short* dst[3] = {VhT, VmT, VlT};
    #pragma unroll
    for (int term = 0; term < 3; ++term) {
      us4 pk;
      #pragma unroll
      for (int i = 0; i < 4; ++i) pk[i] = vs[term][part * 4 + i][row];
      *(us4*)&dst[term][bofs + kt * 2048 + (size_t)row * 32 + tin] = pk;
    }
  }
}

// ---------------------------------------------------------------------------
// 2b) QKV with FUSED 2-way SPLIT-K MERGE of the previous layer.
// ---------------------------------------------------------------------------
__global__ __launch_bounds__(256) void k_qkv_merge(
    float* __restrict__ X,
    const float* __restrict__ Mp, const float* __restrict__ Lp,
    const float* __restrict__ Op,
    const float* __restrict__ WQ, const float* __restrict__ WK,
    const float* __restrict__ WV,
    float* __restrict__ Q,
    unsigned short* __restrict__ Kh, unsigned short* __restrict__ Km,
    unsigned short* __restrict__ Kl,
    unsigned short* __restrict__ VhT, unsigned short* __restrict__ VmT,
    unsigned short* __restrict__ VlT) {
  __shared__ float xs[16][64];
  __shared__ unsigned short vs[3][16][64];
  const int c  = threadIdx.x & 63;
  const int tg = threadIdx.x >> 6;
  const size_t t0 = (size_t)blockIdx.x * 16;
  #pragma unroll
  for (int r = tg; r < 16; r += 4) {
    const size_t grow = t0 + r;                 // global row 0..32767
    const float m0 = Mp[grow], m1 = Mp[32768 + grow];
    const float l0 = Lp[grow], l1 = Lp[32768 + grow];
    const float mm = fmaxf(m0, m1);
    const float w0 = __expf(m0 - mm), w1 = __expf(m1 - mm);
    const float inv = 1.0f / (l0 * w0 + l1 * w1);
    const float o0 = Op[grow * 64 + c];
    const float o1 = Op[(size_t)2097152 + grow * 64 + c];
    const float xn = X[grow * 64 + c] + (o0 * w0 + o1 * w1) * inv;
    X[grow * 64 + c] = xn;
    xs[r][c] = xn;
  }
  __syncthreads();
  float qa[4] = {0.f,0.f,0.f,0.f};
  float ka[4] = {0.f,0.f,0.f,0.f};
  float va[4] = {0.f,0.f,0.f,0.f};
  for (int j = 0; j < 64; ++j) {
    const float wq = WQ[j * 64 + c];
    const float wk = WK[j * 64 + c];
    const float wv = WV[j * 64 + c];
    #pragma unroll
    for (int r = 0; r < 4; ++r) {
      const float x = xs[tg * 4 + r][j];
      qa[r] = fmaf(x, wq, qa[r]);
      ka[r] = fmaf(x, wk, ka[r]);
      va[r] = fmaf(x, wv, va[r]);
    }
  }
  #pragma unroll
  for (int r = 0; r < 4; ++r) {
    const int t = tg * 4 + r;
    const size_t idx = (t0 + t) * 64 + c;
    Q[idx] = qa[r];
    unsigned short h, m, l;
    split3(ka[r], h, m, l);
    Kh[idx] = h; Km[idx] = m; Kl[idx] = l;
    split3(va[r], h, m, l);
    vs[0][t][c] = h; vs[1][t][c] = m; vs[2][t][c] = l;
  }
  __syncthreads();
  {
    const int row  = threadIdx.x >> 2;
    const int part = threadIdx.x & 3;
    const size_t bofs = (t0 >> 10) * ((size_t)DIMN * 64);
    const size_t kt   = (t0 & 1023) >> 5;
    const size_t tin  = (size_t)part * 8 + ((t0 & 31) >> 2);   // sigma permute
    unsigned short* dst[3] = {VhT, VmT, VlT};
    #pragma unroll
    for (int term = 0; term < 3; ++term) {
      us4 pk;
      #pragma unroll
      for (int i = 0; i < 4; ++i) pk[i] = vs[term][part * 4 + i][row];
      *(us4*)&dst[term][bofs + kt * 2048 + (size_t)row * 32 + tin] = pk;
    }
  }
}

// ---------------------------------------------------------------------------
// 3) MFMA flash attention, SPLIT-K (2 halves), SWAPPED QK^T:
//    S = mfma(K, Q) puts one Q-token per lane -> softmax reduce is 7 in-lane
//    ops + 2 shfl_xor; with sigma-permuted V columns the lane's own 8 P
//    values ARE the PV A-fragment (no Pb LDS round-trip, no redistribution).
//    S bits identical (same products, same 6-term chain); only l-sum grouping
//    and PV slot order reorder (round-2-proven safe class).
// ---------------------------------------------------------------------------
__global__ __launch_bounds__(256, 4) void k_attn_sk(
    const float* __restrict__ Qg,
    const unsigned short* __restrict__ Kh, const unsigned short* __restrict__ Km,
    const unsigned short* __restrict__ Kl,
    const unsigned short* __restrict__ VhT, const unsigned short* __restrict__ VmT,
    const unsigned short* __restrict__ VlT,
    float* __restrict__ Mp, float* __restrict__ Lp, float* __restrict__ Op) {
  __shared__ __align__(16) unsigned short Khs[32 * 72];
  __shared__ __align__(16) unsigned short Kms[32 * 72];
  __shared__ __align__(16) unsigned short Kls[32 * 72];
  __shared__ __align__(16) unsigned short Vhs[64 * 40];   // V^T: [c][slot]
  __shared__ __align__(16) unsigned short Vms[64 * 40];
  __shared__ __align__(16) unsigned short Vls[64 * 40];

  const int tid  = threadIdx.x;
  const int w    = tid >> 6;
  const int lane = tid & 63;
  const int ln   = lane & 15;
  const int q    = lane >> 4;

  // XCD-aware swizzle: 1024 blocks; batch pinned to one XCD (locality only)
  const int bid   = blockIdx.x;            // 0..1023
  const int xcd   = bid & 7;
  const int seq   = bid >> 3;              // 0..127
  const int b     = xcd * 4 + (seq >> 5);  // 4 batches per XCD
  const int local = seq & 31;
  const int half  = local >> 4;            // K-split half
  const int i0    = (local & 15) * 64;     // Q tile

  const size_t base = (size_t)b * (DIMN * 64);
  const float scale = 0.03125f;

  const int kj = tid >> 3, kg = tid & 7;
  const int vc = tid >> 2, vg = tid & 3;
  const int klo = kj * 72 + kg * 8;
  const int vlo = vc * 40 + vg * 8;

  // ---- Q fragments: 3-term split (packed), 2 k-chunks (once per block) -----
  bf16x8 qh[2], qm[2], ql[2];
  {
    const int mrow = i0 + 16 * w + ln;
    const float* qp = Qg + base + (size_t)mrow * 64 + 8 * q;
    #pragma unroll
    for (int s = 0; s < 2; ++s) {
      const float4 x0 = ((const float4*)(qp + 32 * s))[0];
      const float4 x1 = ((const float4*)(qp + 32 * s))[1];
      const float xv[8] = {x0.x, x0.y, x0.z, x0.w, x1.x, x1.y, x1.z, x1.w};
      split3_frag(xv, qh[s], qm[s], ql[s]);
    }
  }

  f32x4 O[4];
  #pragma unroll
  for (int ct = 0; ct < 4; ++ct) O[ct] = (f32x4){0.f, 0.f, 0.f, 0.f};
  float m_run = -INFINITY;      // per Q-token (col = ln)
  float l_run = 0.f;

  const int kt0 = half * 16;
  for (int kt = kt0; kt < kt0 + 16; ++kt) {
    __syncthreads();   // previous iteration's K/V readers done

    // ---- stage pre-split K/V tile: pure 16B copies -------------------------
    {
      const size_t tof = base + (size_t)kt * 2048 + tid * 8;  // shorts
      const us8 a0 = *(const us8*)&Kh[tof];
      const us8 a1 = *(const us8*)&Km[tof];
      const us8 a2 = *(const us8*)&Kl[tof];
      const us8 b0 = *(const us8*)&VhT[tof];
      const us8 b1 = *(const us8*)&VmT[tof];
      const us8 b2 = *(const us8*)&VlT[tof];
      *(us8*)&Khs[klo] = a0;
      *(us8*)&Kms[klo] = a1;
      *(us8*)&Kls[klo] = a2;
      *(us8*)&Vhs[vlo] = b0;
      *(us8*)&Vms[vlo] = b1;
      *(us8*)&Vls[vlo] = b2;
    }
    __syncthreads();

    // ---- S strip = mfma(K, Q): rows = K-tokens, cols = Q-tokens ------------
    // sacc[ct][r] = S[K 16ct+4q+r][Q 16w+ln]; same 6-term order as before.
    f32x4 sacc[2];
    #pragma unroll
    for (int ct = 0; ct < 2; ++ct) {
      f32x4 a = (f32x4){0.f, 0.f, 0.f, 0.f};
      #pragma unroll
      for (int s = 0; s < 2; ++s) {
        const int ko = (16 * ct + ln) * 72 + 32 * s + 8 * q;
        const bf16x8 bh = ld16B(&Khs[ko]);
        const bf16x8 bm = ld16B(&Kms[ko]);
        const bf16x8 bl = ld16B(&Kls[ko]);
        a = MFMA16(bh, ql[s], a);
        a = MFMA16(bl, qh[s], a);
        a = MFMA16(bm, qm[s], a);
        a = MFMA16(bh, qm[s], a);
        a = MFMA16(bm, qh[s], a);
        a = MFMA16(bh, qh[s], a);
      }
      sacc[ct] = a;
    }

    // ---- online softmax, per Q-token (one token per lane) ------------------
    float m8 = fmaxf(fmaxf(fmaxf(sacc[0][0], sacc[0][1]),
                           fmaxf(sacc[0][2], sacc[0][3])),
                     fmaxf(fmaxf(sacc[1][0], sacc[1][1]),
                           fmaxf(sacc[1][2], sacc[1][3])));
    m8 = fmaxf(m8, __shfl_xor(m8, 16, 64));
    m8 = fmaxf(m8, __shfl_xor(m8, 32, 64));
    const float mnew  = fmaxf(m_run, m8 * scale);
    const float alpha = __expf(m_run - mnew);
    m_run = mnew;

    float pv[8];
    float s8 = 0.f;
    #pragma unroll
    for (int ct = 0; ct < 2; ++ct) {
      #pragma unroll
      for (int r = 0; r < 4; ++r) {
        const float p = __expf(sacc[ct][r] * scale - m_run);
        pv[ct * 4 + r] = p;
        s8 += p;
      }
    }
    float sr = s8 + __shfl_xor(s8, 16, 64);
    sr = sr + __shfl_xor(sr, 32, 64);
    l_run = l_run * alpha + sr;

    // alpha broadcast to O-row layout (row token = 4q+r lives at lane 4q+r)
    const int srcb = (lane & 48) + ((lane & 48) >> 2);
    float arow[4];
    #pragma unroll
    for (int r = 0; r < 4; ++r) arow[r] = __shfl(alpha, srcb + r, 64);
    #pragma unroll
    for (int ct = 0; ct < 4; ++ct) {
      #pragma unroll
      for (int r = 0; r < 4; ++r) O[ct][r] *= arow[r];
    }

    // ---- P A-fragment = own pv in slot order (sigma) -----------------------
    bf16x8 ph, pm, pl;
    split3_frag(pv, ph, pm, pl);

    // ---- O += P @ V, 6-product (r5 order) ----------------------------------
    #pragma unroll
    for (int ct = 0; ct < 4; ++ct) {
      const int vo = (16 * ct + ln) * 40 + 8 * q;
      const bf16x8 vvh = ld16B(&Vhs[vo]);
      const bf16x8 vvm = ld16B(&Vms[vo]);
      const bf16x8 vvl = ld16B(&Vls[vo]);
      O[ct] = MFMA16(ph, vvh, O[ct]);
      O[ct] = MFMA16(ph, vvm, O[ct]);
      O[ct] = MFMA16(pm, vvh, O[ct]);
      O[ct] = MFMA16(pm, vvm, O[ct]);
      O[ct] = MFMA16(ph, vvl, O[ct]);
      O[ct] = MFMA16(pl, vvh, O[ct]);
    }
  }

  // ---- epilogue: write split-K partials (m, l, raw O) ----------------------
  const size_t hofs = (size_t)half * (32 * 1024);
  #pragma unroll
  for (int r = 0; r < 4; ++r) {
    const int row = i0 + 16 * w + 4 * q + r;
    const size_t grow = hofs + (size_t)b * DIMN + row;
    #pragma unroll
    for (int ct = 0; ct < 4; ++ct)
      Op[grow * 64 + ln + 16 * ct] = O[ct][r];
  }
  if (q == 0) {
    const size_t tgrow = hofs + (size_t)b * DIMN + i0 + 16 * w + ln;
    Mp[tgrow] = m_run;
    Lp[tgrow] = l_run;
  }
}

// ---------------------------------------------------------------------------
// 3b) final merge + channel-mean (layer 7 partials): 256 blocks x 128 tokens
// ---------------------------------------------------------------------------
__global__ __launch_bounds__(256) void k_merge_mean(
    const float* __restrict__ X,
    const float* __restrict__ Mp, const float* __restrict__ Lp,
    const float* __restrict__ Op, float* __restrict__ meanv) {
  const int c  = threadIdx.x & 63;
  const int tg = threadIdx.x >> 6;
  const size_t t0 = (size_t)blockIdx.x * 128;
  for (int i = tg; i < 128; i += 4) {
    const size_t grow = t0 + i;
    const float m0 = Mp[grow], m1 = Mp[32768 + grow];
    const float l0 = Lp[grow], l1 = Lp[32768 + grow];
    const float mm = fmaxf(m0, m1);
    const float w0 = __expf(m0 - mm), w1 = __expf(m1 - mm);
    const float inv = 1.0f / (l0 * w0 + l1 * w1);
    const float o0 = Op[grow * 64 + c];
    const float o1 = Op[(size_t)2097152 + grow * 64 + c];
    float v = X[grow * 64 + c] + (o0 * w0 + o1 * w1) * inv;
    #pragma unroll
    for (int off = 32; off > 0; off >>= 1)
      v += __shfl_down(v, off, 64);
    if (c == 0) meanv[grow] = v * (1.0f / 64.0f);
  }
}

// ---------------------------------------------------------------------------
// 4) head stage 2: pred[b,k] = meanv[b,:] . last_W[k,:] + last_b[k]
// ---------------------------------------------------------------------------
__global__ __launch_bounds__(256) void k_head2(
    const float* __restrict__ meanv, const float* __restrict__ lW,
    const float* __restrict__ lb, float* __restrict__ out) {
  __shared__ float red[256];
  const int b   = blockIdx.x;
  const int tid = threadIdx.x;
  float acc[NCLS];
  #pragma unroll
  for (int k = 0; k < NCLS; ++k) acc[k] = 0.f;
  for (int n = tid; n < DIMN; n += 256) {
    const float m = meanv[(size_t)b * DIMN + n];
    #pragma unroll
    for (int k = 0; k < NCLS; ++k)
      acc[k] = fmaf(m, lW[k * DIMN + n], acc[k]);
  }
  for (int k = 0; k < NCLS; ++k) {
    red[tid] = acc[k];
    __syncthreads();
    for (int s = 128; s > 0; s >>= 1) {
      if (tid < s) red[tid] += red[tid + s];
      __syncthreads();
    }
    if (tid == 0) out[b * NCLS + k] = red[0] + lb[k];
    __syncthreads();
  }
}

// ===========================================================================
// MIDDLE-TIER PATH (ws >= 41 MB but < split-K need): same swapped structure
// ===========================================================================
__global__ __launch_bounds__(256) void k_attn_s(
    const float* __restrict__ Qg,
    const unsigned short* __restrict__ Kh, const unsigned short* __restrict__ Km,
    const unsigned short* __restrict__ Kl,
    const unsigned short* __restrict__ VhT, const unsigned short* __restrict__ VmT,
    const unsigned short* __restrict__ VlT,
    float* __restrict__ X, float* __restrict__ meanout) {
  __shared__ __align__(16) unsigned short Khs[32 * 72];
  __shared__ __align__(16) unsigned short Kms[32 * 72];
  __shared__ __align__(16) unsigned short Kls[32 * 72];
  __shared__ __align__(16) unsigned short Vhs[64 * 40];
  __shared__ __align__(16) unsigned short Vms[64 * 40];
  __shared__ __align__(16) unsigned short Vls[64 * 40];

  const int tid  = threadIdx.x;
  const int w    = tid >> 6;
  const int lane = tid & 63;
  const int ln   = lane & 15;
  const int q    = lane >> 4;
  const int bid = blockIdx.x;
  const int xcd = bid & 7;
  const int seq = bid >> 3;
  const int b   = xcd * 4 + (seq >> 4);
  const int i0  = (seq & 15) * 64;
  const size_t base = (size_t)b * (DIMN * 64);
  const float scale = 0.03125f;

  const int kj = tid >> 3, kg = tid & 7;
  const int vc = tid >> 2, vg = tid & 3;
  const int klo = kj * 72 + kg * 8;
  const int vlo = vc * 40 + vg * 8;

  bf16x8 qh[2], qm[2], ql[2];
  {
    const int mrow = i0 + 16 * w + ln;
    const float* qp = Qg + base + (size_t)mrow * 64 + 8 * q;
    #pragma unroll
    for (int s = 0; s < 2; ++s) {
      const float4 x0 = ((const float4*)(qp + 32 * s))[0];
      const float4 x1 = ((const float4*)(qp + 32 * s))[1];
      const float xv[8] = {x0.x, x0.y, x0.z, x0.w, x1.x, x1.y, x1.z, x1.w};
      split3_frag(xv, qh[s], qm[s], ql[s]);
    }
  }

  f32x4 O[4];
  #pragma unroll
  for (int ct = 0; ct < 4; ++ct) O[ct] = (f32x4){0.f, 0.f, 0.f, 0.f};
  float m_run = -INFINITY;
  float l_run = 0.f;

  for (int kt = 0; kt < 32; ++kt) {
    __syncthreads();
    {
      const size_t tof = base + (size_t)kt * 2048 + tid * 8;
      const us8 a0 = *(const us8*)&Kh[tof];
      const us8 a1 = *(const us8*)&Km[tof];
      const us8 a2 = *(const us8*)&Kl[tof];
      const us8 b0 = *(const us8*)&VhT[tof];
      const us8 b1 = *(const us8*)&VmT[tof];
      const us8 b2 = *(const us8*)&VlT[tof];
      *(us8*)&Khs[klo] = a0;
      *(us8*)&Kms[klo] = a1;
      *(us8*)&Kls[klo] = a2;
      *(us8*)&Vhs[vlo] = b0;
      *(us8*)&Vms[vlo] = b1;
      *(us8*)&Vls[vlo] = b2;
    }
    __syncthreads();

    f32x4 sacc[2];
    #pragma unroll
    for (int ct = 0; ct < 2; ++ct) {
      f32x4 a = (f32x4){0.f, 0.f, 0.f, 0.f};
      #pragma unroll
      for (int s = 0; s < 2; ++s) {
        const int ko = (16 * ct + ln) * 72 + 32 * s + 8 * q;
        const bf16x8 bh = ld16B(&Khs[ko]);
        const bf16x8 bm = ld16B(&Kms[ko]);
        const bf16x8 bl = ld16B(&Kls[ko]);
        a = MFMA16(bh, ql[s], a);
        a = MFMA16(bl, qh[s], a);
        a = MFMA16(bm, qm[s], a);
        a = MFMA16(bh, qm[s], a);
        a = MFMA16(bm, qh[s], a);
        a = MFMA16(bh, qh[s], a);
      }
      sacc[ct] = a;
    }

    float m8 = fmaxf(fmaxf(fmaxf(sacc[0][0], sacc[0][1]),
                           fmaxf(sacc[0][2], sacc[0][3])),
                     fmaxf(fmaxf(sacc[1][0], sacc[1][1]),
                           fmaxf(sacc[1][2], sacc[1][3])));
    m8 = fmaxf(m8, __shfl_xor(m8, 16, 64));
    m8 = fmaxf(m8, __shfl_xor(m8, 32, 64));
    const float mnew  = fmaxf(m_run, m8 * scale);
    const float alpha = __expf(m_run - mnew);
    m_run = mnew;

    float pv[8];
    float s8 = 0.f;
    #pragma unroll
    for (int ct = 0; ct < 2; ++ct) {
      #pragma unroll
      for (int r = 0; r < 4; ++r) {
        const float p = __expf(sacc[ct][r] * scale - m_run);
        pv[ct * 4 + r] = p;
        s8 += p;
      }
    }
    float sr = s8 + __shfl_xor(s8, 16, 64);
    sr = sr + __shfl_xor(sr, 32, 64);
    l_run = l_run * alpha + sr;

    const int srcb = (lane & 48) + ((lane & 48) >> 2);
    float arow[4];
    #pragma unroll
    for (int r = 0; r < 4; ++r) arow[r] = __shfl(alpha, srcb + r, 64);
    #pragma unroll
    for (int ct = 0; ct < 4; ++ct) {
      #pragma unroll
      for (int r = 0; r < 4; ++r) O[ct][r] *= arow[r];
    }

    bf16x8 ph, pm, pl;
    split3_frag(pv, ph, pm, pl);

    #pragma unroll
    for (int ct = 0; ct < 4; ++ct) {
      const int vo = (16 * ct + ln) * 40 + 8 * q;
      const bf16x8 vvh = ld16B(&Vhs[vo]);
      const bf16x8 vvm = ld16B(&Vms[vo]);
      const bf16x8 vvl = ld16B(&Vls[vo]);
      O[ct] = MFMA16(ph, vvh, O[ct]);
      O[ct] = MFMA16(ph, vvm, O[ct]);
      O[ct] = MFMA16(pm, vvh, O[ct]);
      O[ct] = MFMA16(pm, vvm, O[ct]);
      O[ct] = MFMA16(ph, vvl, O[ct]);
      O[ct] = MFMA16(pl, vvh, O[ct]);
    }
  }

  // l for O-rows (token 4q+r) via bpermute from token lanes
  const int srcb = (lane & 48) + ((lane & 48) >> 2);
  float linv[4];
  #pragma unroll
  for (int r = 0; r < 4; ++r) linv[r] = 1.0f / __shfl(l_run, srcb + r, 64);
  #pragma unroll
  for (int r = 0; r < 4; ++r) {
    const int row = i0 + 16 * w + 4 * q + r;
    float srow = 0.f;
    #pragma unroll
    for (int ct = 0; ct < 4; ++ct) {
      float* xp = X + base + (size_t)row * 64 + ln + 16 * ct;
      const float nv = *xp + O[ct][r] * linv[r];
      *xp = nv;
      srow += nv;
    }
    if (meanout) {
      #pragma unroll
      for (int mk = 1; mk <= 8; mk <<= 1)
        srow += __shfl_xor(srow, mk, 64);
      if (ln == 0) meanout[(size_t)b * DIMN + row] = srow * (1.0f / 64.0f);
    }
  }
}

// ---------------------------------------------------------------------------
// launch
// ---------------------------------------------------------------------------
extern "C" void kernel_launch(void* const* d_in, const int* in_sizes, int n_in,
                              void* d_out, int out_size, void* d_ws, size_t ws_size,
                              hipStream_t stream) {
  const float* image = (const float*)d_in[0];
  const float* WV    = (const float*)d_in[1];
  const float* WK    = (const float*)d_in[2];
  const float* WQ    = (const float*)d_in[3];
  const float* lW    = (const float*)d_in[4];
  const float* lb    = (const float*)d_in[5];
  float* out = (float*)d_out;

  float* ws = (float*)d_ws;
  const size_t NELEM = (size_t)BB * DIMN * CCH;   // 2,097,152
  const size_t NROW  = (size_t)BB * DIMN;         // 32,768

  // layout (floats): X | Q | KVsplits(3N) | Op(2N) | Mp(2R) | Lp(2R) | meanv(R)
  const size_t need_sk   = (7 * NELEM + 5 * NROW) * sizeof(float);
  const size_t need_fast = (5 * NELEM + NROW) * sizeof(float);

  if (ws_size >= need_sk) {
    float* X = ws;
    float* Q = ws + NELEM;
    unsigned short* Kh  = (unsigned short*)(ws + 2 * NELEM);
    unsigned short* Km  = Kh + NELEM;
    unsigned short* Kl  = Kh + 2 * NELEM;
    unsigned short* VhT = Kh + 3 * NELEM;
    unsigned short* VmT = Kh + 4 * NELEM;
    unsigned short* VlT = Kh + 5 * NELEM;
    float* Op    = ws + 5 * NELEM;
    float* Mp    = ws + 7 * NELEM;
    float* Lp    = Mp + 2 * NROW;
    float* meanv = Lp + 2 * NROW;

    k_transpose<<<dim3(DIMN / 64, BB), 256, 0, stream>>>(image, X);
    k_qkv_split<<<(BB * DIMN) / 16, 256, 0, stream>>>(
        X, WQ, WK, WV, Q, Kh, Km, Kl, VhT, VmT, VlT);
    for (int layer = 0; layer < 8; ++layer) {
      k_attn_sk<<<1024, 256, 0, stream>>>(
          Q, Kh, Km, Kl, VhT, VmT, VlT, Mp, Lp, Op);
      if (layer < 7)
        k_qkv_merge<<<(BB * DIMN) / 16, 256, 0, stream>>>(
            X, Mp, Lp, Op, WQ, WK, WV, Q, Kh, Km, Kl, VhT, VmT, VlT);
    }
    k_merge_mean<<<256, 256, 0, stream>>>(X, Mp, Lp, Op, meanv);
    k_head2<<<BB, 256, 0, stream>>>(meanv, lW, lb, out);
  } else {
    // middle tier
    float* X = ws;
    float* Q = ws + NELEM;
    unsigned short* Kh  = (unsigned short*)(ws + 2 * NELEM);
    unsigned short* Km  = Kh + NELEM;
    unsigned short* Kl  = Kh + 2 * NELEM;
    unsigned short* VhT = Kh + 3 * NELEM;
    unsigned short* VmT = Kh + 4 * NELEM;
    unsigned short* VlT = Kh + 5 * NELEM;
    float* meanv = ws + 5 * NELEM;
    (void)need_fast;

    k_transpose<<<dim3(DIMN / 64, BB), 256, 0, stream>>>(image, X);
    for (int layer = 0; layer < 8; ++layer) {
      k_qkv_split<<<(BB * DIMN) / 16, 256, 0, stream>>>(
          X, WQ, WK, WV, Q, Kh, Km, Kl, VhT, VmT, VlT);
      k_attn_s<<<512, 256, 0, stream>>>(
          Q, Kh, Km, Kl, VhT, VmT, VlT, X, (layer == 7) ? meanv : nullptr);
    }
    k_head2<<<BB, 256, 0, stream>>>(meanv, lW, lb, out);
  }
}